// Round 1
// baseline (2572.565 us; speedup 1.0000x reference)
//
#include <hip/hip_runtime.h>

// Problem constants
constexpr int CB = 32, CL = 256, CS = 5, CN = 1024, CD = 256, CV = 512, CH = 8, CDh = 32;

// ---------------------------------------------------------------------------
// Fold conv into W_fold^T:  wfT[(si*256+ci)*256 + j] = coefficient of
// emb_w[tok@si][ci] in q_mean[j].  q_mean[b,l,j] = (1/5) sum_i conv_out[n, c_ij, s_ij]
// with c_ij=(i*256+j)/5, s_ij=(i*256+j)%5; conv taps k=0..2 hit input pos s+k-1.
__global__ void build_wfold(const float* __restrict__ conv_w, float* __restrict__ wfT) {
    const int j = blockIdx.x;      // 0..255
    const int ci = threadIdx.x;    // 0..255
    float acc[5] = {0.f, 0.f, 0.f, 0.f, 0.f};
#pragma unroll
    for (int i = 0; i < 5; ++i) {
        int flat = i * 256 + j;
        int c = flat / 5;
        int s = flat % 5;
#pragma unroll
        for (int k = 0; k < 3; ++k) {
            int si = s + k - 1;
            if (si >= 0 && si < 5) acc[si] += conv_w[(c * 256 + ci) * 3 + k];
        }
    }
#pragma unroll
    for (int si = 0; si < 5; ++si)
        wfT[(si * 256 + ci) * 256 + j] = acc[si] * 0.2f;
}

// ---------------------------------------------------------------------------
// Generic tiled fp32 GEMM: C[row, col] = sum_k A[row,k] * W[col,k] (+ bias[col])
// 64x64 block tile, 32 k-chunk, 4x4 register micro-tile per thread (256 thr).
// blockIdx.z slices A/W/C by the given strides (for per-s / per-side batching).
template <bool BIAS>
__global__ __launch_bounds__(256) void gemm64(const float* __restrict__ A,
                                              const float* __restrict__ W,
                                              const float* __restrict__ bias,
                                              float* __restrict__ C,
                                              int K, int ldC,
                                              long sliceA, long sliceW, long sliceC) {
    A += (long)blockIdx.z * sliceA;
    W += (long)blockIdx.z * sliceW;
    C += (long)blockIdx.z * sliceC;
    const int row0 = blockIdx.x * 64;
    const int col0 = blockIdx.y * 64;
    __shared__ float As[32][68];   // [kc][r], padded; 16B-aligned float4 rows
    __shared__ float Ws[32][68];
    const int t = threadIdx.x;
    const int tx = t & 15;   // col group
    const int ty = t >> 4;   // row group
    float acc[4][4] = {};
    for (int kk = 0; kk < K; kk += 32) {
#pragma unroll
        for (int e = 0; e < 8; ++e) {
            int f = t + 256 * e;
            int r = f >> 5, kc = f & 31;
            As[kc][r] = A[(long)(row0 + r) * K + kk + kc];
            Ws[kc][r] = W[(long)(col0 + r) * K + kk + kc];
        }
        __syncthreads();
#pragma unroll
        for (int kc = 0; kc < 32; ++kc) {
            float4 a4 = *(const float4*)&As[kc][ty * 4];
            float4 w4 = *(const float4*)&Ws[kc][tx * 4];
            float av[4] = {a4.x, a4.y, a4.z, a4.w};
            float wv[4] = {w4.x, w4.y, w4.z, w4.w};
#pragma unroll
            for (int i = 0; i < 4; ++i)
#pragma unroll
                for (int jj = 0; jj < 4; ++jj)
                    acc[i][jj] += av[i] * wv[jj];
        }
        __syncthreads();
    }
#pragma unroll
    for (int r = 0; r < 4; ++r) {
        int row = row0 + ty * 4 + r;
#pragma unroll
        for (int c = 0; c < 4; ++c) {
            int col = col0 + tx * 4 + c;
            float v = acc[r][c];
            if (BIAS) v += bias[col];
            C[(long)row * ldC + col] = v;
        }
    }
}

// ---------------------------------------------------------------------------
// bias_dir[d] = sum_j txt_proj_w[d,j]*dir[j] + txt_proj_b[d]   (block 0: L, 1: R)
__global__ void bias_dir_kernel(const float* __restrict__ tp, const float* __restrict__ tpb,
                                const float* __restrict__ dirL, const float* __restrict__ dirR,
                                float* __restrict__ biasL, float* __restrict__ biasR) {
    const float* dir = blockIdx.x ? dirR : dirL;
    float* outp = blockIdx.x ? biasR : biasL;
    __shared__ float sdir[256];
    const int d = threadIdx.x;
    sdir[d] = dir[d];
    __syncthreads();
    float acc = tpb[d];
    for (int j = 0; j < 256; ++j) acc += tp[d * 256 + j] * sdir[j];
    outp[d] = acc;
}

// ---------------------------------------------------------------------------
// Q build: gather 5 rows of P, add dir-bias, LayerNorm -> Q[b*L+l, d]
__global__ __launch_bounds__(256) void q_build(const int* __restrict__ idsL, const int* __restrict__ idsR,
                                               const float* __restrict__ P_L, const float* __restrict__ P_R,
                                               const float* __restrict__ biasL, const float* __restrict__ biasR,
                                               const float* __restrict__ qg, const float* __restrict__ qb,
                                               float* __restrict__ Q_L, float* __restrict__ Q_R) {
    const int bl = blockIdx.x;
    const bool right = blockIdx.y != 0;
    const int* ids = right ? idsR : idsL;
    const float* P = right ? P_R : P_L;
    const float* bias = right ? biasR : biasL;
    float* Q = right ? Q_R : Q_L;
    const int d = threadIdx.x;
    __shared__ int toks[5];
    if (d < 5) toks[d] = ids[bl * 5 + d];
    __syncthreads();
    float acc = bias[d];
#pragma unroll
    for (int s = 0; s < 5; ++s)
        acc += P[((s * 512) + toks[s]) * 256 + d];
    __shared__ float red[256];
    red[d] = acc;
    __syncthreads();
    for (int st = 128; st; st >>= 1) { if (d < st) red[d] += red[d + st]; __syncthreads(); }
    float mean = red[0] * (1.0f / 256.0f);
    __syncthreads();
    float dv = acc - mean;
    red[d] = dv * dv;
    __syncthreads();
    for (int st = 128; st; st >>= 1) { if (d < st) red[d] += red[d + st]; __syncthreads(); }
    float var = red[0] * (1.0f / 256.0f);
    Q[(long)bl * 256 + d] = dv * rsqrtf(var + 1e-5f) * qg[d] + qb[d];
}

// ---------------------------------------------------------------------------
// In-place row LayerNorm for K (y=0) and V (y=1)
__global__ __launch_bounds__(256) void ln_rows(float* __restrict__ Kb, float* __restrict__ Vb,
                                               const float* __restrict__ gamma, const float* __restrict__ beta) {
    float* ptr = (blockIdx.y ? Vb : Kb) + (long)blockIdx.x * 256;
    const int t = threadIdx.x;
    float x = ptr[t];
    __shared__ float red[256];
    red[t] = x;
    __syncthreads();
    for (int st = 128; st; st >>= 1) { if (t < st) red[t] += red[t + st]; __syncthreads(); }
    float mean = red[0] * (1.0f / 256.0f);
    __syncthreads();
    float dv = x - mean;
    red[t] = dv * dv;
    __syncthreads();
    for (int st = 128; st; st >>= 1) { if (t < st) red[t] += red[t + st]; __syncthreads(); }
    float var = red[0] * (1.0f / 256.0f);
    ptr[t] = dv * rsqrtf(var + 1e-5f) * gamma[t] + beta[t];
}

// ---------------------------------------------------------------------------
// Fused cross-attention: block = (l-tile of 8, head, b*2+side). 256 threads.
// scores in LDS (8 x 1024), softmax via 32-lane shuffles, PV accumulate.
__global__ __launch_bounds__(256) void attn_kernel(const float* __restrict__ Q_L, const float* __restrict__ Q_R,
                                                   const float* __restrict__ Kb, const float* __restrict__ Vb,
                                                   const float* __restrict__ vis_mask, const float* __restrict__ tau_p,
                                                   float* __restrict__ F_L, float* __restrict__ F_R) {
    const int lt = blockIdx.x;            // 0..31
    const int h = blockIdx.y;             // 0..7
    const int b = blockIdx.z >> 1;        // 0..31
    const bool right = blockIdx.z & 1;
    const float* Q = right ? Q_R : Q_L;
    float* F = right ? F_R : F_L;
    float tau = tau_p[0];
    tau = fminf(fmaxf(tau, 0.25f), 4.0f);
    const float invscale = 1.0f / (5.656854249492381f * tau);  // 1/(sqrt(32)*tau)

    __shared__ float q_s[8][33];
    __shared__ float k_s[64][33];
    __shared__ float v_s[64][33];
    __shared__ float s_s[8][1028];

    const int t = threadIdx.x;
    const int lq = t >> 5;     // 0..7 : l row handled by this 32-lane group
    const int dh = t & 31;
    const int l0 = lt * 8;
    const long qoff = (long)(b * CL + l0 + lq) * 256 + h * 32 + dh;
    q_s[lq][dh] = Q[qoff];
    __syncthreads();

    // ---- scores = Q . K^T ----
    for (int nt = 0; nt < 16; ++nt) {
#pragma unroll
        for (int e = 0; e < 8; ++e) {
            int f = t + 256 * e;
            int nn = f >> 5, dd = f & 31;
            k_s[nn][dd] = Kb[((long)b * CN + nt * 64 + nn) * 256 + h * 32 + dd];
        }
        __syncthreads();
#pragma unroll
        for (int e = 0; e < 2; ++e) {
            int nn = (t & 31) + 32 * e;
            float acc = 0.f;
#pragma unroll
            for (int kd = 0; kd < 32; ++kd) acc += q_s[lq][kd] * k_s[nn][kd];
            s_s[lq][nt * 64 + nn] = acc;
        }
        __syncthreads();
    }

    // ---- scale * mask, softmax over N (row owned by 32 contiguous lanes) ----
    const float* mrow = vis_mask + (long)(b * CL + l0 + lq) * CN;
    float m = -1e30f;
    for (int e = 0; e < 32; ++e) {
        int nn = (t & 31) + 32 * e;
        float v = s_s[lq][nn] * invscale * mrow[nn];
        s_s[lq][nn] = v;
        m = fmaxf(m, v);
    }
#pragma unroll
    for (int off = 16; off; off >>= 1) m = fmaxf(m, __shfl_xor(m, off, 32));
    float sum = 0.f;
    for (int e = 0; e < 32; ++e) {
        int nn = (t & 31) + 32 * e;
        float v = expf(s_s[lq][nn] - m);
        s_s[lq][nn] = v;
        sum += v;
    }
#pragma unroll
    for (int off = 16; off; off >>= 1) sum += __shfl_xor(sum, off, 32);
    const float rsum = 1.0f / sum;
    for (int e = 0; e < 32; ++e) {
        int nn = (t & 31) + 32 * e;
        s_s[lq][nn] *= rsum;
    }
    __syncthreads();

    // ---- out = attn . V ----
    float acc = 0.f;
    for (int nt = 0; nt < 16; ++nt) {
#pragma unroll
        for (int e = 0; e < 8; ++e) {
            int f = t + 256 * e;
            int nn = f >> 5, dd = f & 31;
            v_s[nn][dd] = Vb[((long)b * CN + nt * 64 + nn) * 256 + h * 32 + dd];
        }
        __syncthreads();
#pragma unroll
        for (int nn = 0; nn < 64; ++nn)
            acc += s_s[lq][nt * 64 + nn] * v_s[nn][dh];
        __syncthreads();
    }
    F[qoff] = acc;
}

// ---------------------------------------------------------------------------
// Loss: per (b, l in 0..254): softmax(logits_l[b,l]/2), softmax(logits_r[b,l+1]/2),
// sum of squared diff * tgt_mask -> atomicAdd.
__global__ __launch_bounds__(256) void loss_pair(const float* __restrict__ logits,
                                                 const float* __restrict__ tgt_mask,
                                                 float* __restrict__ accp) {
    const int l = blockIdx.x;   // 0..254
    const int b = blockIdx.y;
    const int t = threadIdx.x;
    const float* ll = logits + (long)(b * 256 + l) * 512;
    const float* lr = logits + 4194304 + (long)(b * 256 + l + 1) * 512;
    float a0 = ll[t] * 0.5f, a1 = ll[t + 256] * 0.5f;
    float c0 = lr[t] * 0.5f, c1 = lr[t + 256] * 0.5f;
    __shared__ float red[256];
    auto bmax = [&](float v) -> float {
        red[t] = v; __syncthreads();
        for (int st = 128; st; st >>= 1) { if (t < st) red[t] = fmaxf(red[t], red[t + st]); __syncthreads(); }
        float r = red[0]; __syncthreads(); return r;
    };
    auto bsum = [&](float v) -> float {
        red[t] = v; __syncthreads();
        for (int st = 128; st; st >>= 1) { if (t < st) red[t] += red[t + st]; __syncthreads(); }
        float r = red[0]; __syncthreads(); return r;
    };
    float ml = bmax(fmaxf(a0, a1));
    float e0 = expf(a0 - ml), e1 = expf(a1 - ml);
    float sl = bsum(e0 + e1);
    float p0 = e0 / sl, p1 = e1 / sl;
    float mr = bmax(fmaxf(c0, c1));
    float f0 = expf(c0 - mr), f1 = expf(c1 - mr);
    float sr = bsum(f0 + f1);
    float q0 = f0 / sr, q1 = f1 / sr;
    float d0 = p0 - q0, d1 = p1 - q1;
    float sq = bsum(d0 * d0 + d1 * d1);
    if (t == 0) atomicAdd(accp, sq * tgt_mask[b * 256 + l]);
}

__global__ __launch_bounds__(256) void loss_final(const float* __restrict__ tgt_mask,
                                                  const float* __restrict__ accp,
                                                  float* __restrict__ outp) {
    const int t = threadIdx.x;
    float s = 0.f;
    for (int i = t; i < 32 * 255; i += 256) {
        int b = i / 255, l = i % 255;
        s += tgt_mask[b * 256 + l];
    }
    __shared__ float red[256];
    red[t] = s;
    __syncthreads();
    for (int st = 128; st; st >>= 1) { if (t < st) red[t] += red[t + st]; __syncthreads(); }
    if (t == 0) outp[0] = 0.1f * accp[0] / fmaxf(red[0], 1.0f);
}

// ---------------------------------------------------------------------------
extern "C" void kernel_launch(void* const* d_in, const int* in_sizes, int n_in,
                              void* d_out, int out_size, void* d_ws, size_t ws_size,
                              hipStream_t stream) {
    const float* vis_tokens = (const float*)d_in[0];
    const int* idsL = (const int*)d_in[1];
    const int* idsR = (const int*)d_in[2];
    // d_in[3] tgt_ids unused by the reference
    const float* tgt_mask = (const float*)d_in[4];
    const float* vis_mask = (const float*)d_in[5];
    const float* emb_w = (const float*)d_in[6];
    const float* dirL = (const float*)d_in[7];
    const float* dirR = (const float*)d_in[8];
    const float* tp_w = (const float*)d_in[9];
    const float* tp_b = (const float*)d_in[10];
    const float* q_g = (const float*)d_in[11];
    const float* q_b = (const float*)d_in[12];
    const float* k_w = (const float*)d_in[13];
    const float* k_b = (const float*)d_in[14];
    const float* v_w = (const float*)d_in[15];
    const float* v_b = (const float*)d_in[16];
    const float* kv_g = (const float*)d_in[17];
    const float* kv_b = (const float*)d_in[18];
    const float* tau = (const float*)d_in[19];
    const float* cls_b = (const float*)d_in[20];
    const float* conv_l = (const float*)d_in[21];
    const float* conv_r = (const float*)d_in[22];
    float* out = (float*)d_out;
    float* ws = (float*)d_ws;

    // workspace layout (floats)
    float* Kbuf = ws;                       // 32768*256
    float* Vbuf = Kbuf + 8388608;           // 32768*256
    float* Q_l = Vbuf + 8388608;            // 8192*256
    float* Q_r = Q_l + 2097152;
    float* F_l = Q_r + 2097152;
    float* F_r = F_l + 2097152;
    float* wfT_l = F_r + 2097152;           // 5*256*256
    float* wfT_r = wfT_l + 327680;
    float* Ms_l = wfT_r + 327680;           // 5*256*256
    float* Ms_r = Ms_l + 327680;
    float* P_l = Ms_r + 327680;             // 5*512*256
    float* P_r = P_l + 655360;
    float* bias_l = P_r + 655360;           // 256
    float* bias_r = bias_l + 256;
    float* accp = bias_r + 256;             // 1

    hipMemsetAsync(accp, 0, sizeof(float), stream);

    // --- ctx path fold: wfT -> Ms -> P ---
    build_wfold<<<256, 256, 0, stream>>>(conv_l, wfT_l);
    build_wfold<<<256, 256, 0, stream>>>(conv_r, wfT_r);
    // Ms_s[d,ci] = sum_j tp[d,j] * wfT_s[ci,j]
    gemm64<false><<<dim3(4, 4, 5), 256, 0, stream>>>(tp_w, wfT_l, nullptr, Ms_l, 256, 256, 0, 65536, 65536);
    gemm64<false><<<dim3(4, 4, 5), 256, 0, stream>>>(tp_w, wfT_r, nullptr, Ms_r, 256, 256, 0, 65536, 65536);
    // P_s[t,d] = sum_ci emb_w[t,ci] * Ms_s[d,ci]
    gemm64<false><<<dim3(8, 4, 5), 256, 0, stream>>>(emb_w, Ms_l, nullptr, P_l, 256, 256, 0, 65536, 131072);
    gemm64<false><<<dim3(8, 4, 5), 256, 0, stream>>>(emb_w, Ms_r, nullptr, P_r, 256, 256, 0, 65536, 131072);
    bias_dir_kernel<<<2, 256, 0, stream>>>(tp_w, tp_b, dirL, dirR, bias_l, bias_r);
    q_build<<<dim3(8192, 2), 256, 0, stream>>>(idsL, idsR, P_l, P_r, bias_l, bias_r, q_g, q_b, Q_l, Q_r);

    // --- K/V projections + LN ---
    gemm64<true><<<dim3(512, 4, 1), 256, 0, stream>>>(vis_tokens, k_w, k_b, Kbuf, 256, 256, 0, 0, 0);
    gemm64<true><<<dim3(512, 4, 1), 256, 0, stream>>>(vis_tokens, v_w, v_b, Vbuf, 256, 256, 0, 0, 0);
    ln_rows<<<dim3(32768, 2), 256, 0, stream>>>(Kbuf, Vbuf, kv_g, kv_b);

    // --- fused cross-attention (both sides) ---
    attn_kernel<<<dim3(32, 8, 64), 256, 0, stream>>>(Q_l, Q_r, Kbuf, Vbuf, vis_mask, tau, F_l, F_r);

    // --- tied classifier logits straight into d_out (+1 float offset) ---
    gemm64<true><<<dim3(128, 8, 2), 256, 0, stream>>>(F_l, emb_w, cls_b, out + 1, 256, 512,
                                                      2097152, 0, 4194304);

    // --- SGM agreement loss ---
    loss_pair<<<dim3(255, 32), 256, 0, stream>>>(out + 1, tgt_mask, accp);
    loss_final<<<1, 256, 0, stream>>>(tgt_mask, accp, out);
}

// Round 2
// 602.761 us; speedup vs baseline: 4.2680x; 4.2680x over previous
//
#include <hip/hip_runtime.h>

typedef __attribute__((ext_vector_type(8))) short short8;
typedef __attribute__((ext_vector_type(4))) float f32x4;

__device__ __forceinline__ short f2bf(float x) {
    union { float f; unsigned u; } c; c.f = x;
    unsigned u = c.u;
    u += 0x7fffu + ((u >> 16) & 1u);
    return (short)(u >> 16);
}
__device__ __forceinline__ float bf2f(short x) {
    union { unsigned u; float f; } c; c.u = ((unsigned)(unsigned short)x) << 16;
    return c.f;
}

// ---------------------------------------------------------------------------
// fp32 -> bf16 bulk convert (n multiple of 4)
__global__ __launch_bounds__(256) void cvt_bf16(const float* __restrict__ s, short* __restrict__ d, int n4) {
    int i = blockIdx.x * 256 + threadIdx.x;
    if (i < n4) {
        float4 v = ((const float4*)s)[i];
        short4 o;
        o.x = f2bf(v.x); o.y = f2bf(v.y); o.z = f2bf(v.z); o.w = f2bf(v.w);
        ((short4*)d)[i] = o;
    }
}

// ---------------------------------------------------------------------------
// Fold conv into W_fold^T (see R1 derivation)
__global__ void build_wfold(const float* __restrict__ conv_w, float* __restrict__ wfT) {
    const int j = blockIdx.x;
    const int ci = threadIdx.x;
    float acc[5] = {0.f, 0.f, 0.f, 0.f, 0.f};
#pragma unroll
    for (int i = 0; i < 5; ++i) {
        int flat = i * 256 + j;
        int c = flat / 5;
        int s = flat % 5;
#pragma unroll
        for (int k = 0; k < 3; ++k) {
            int si = s + k - 1;
            if (si >= 0 && si < 5) acc[si] += conv_w[(c * 256 + ci) * 3 + k];
        }
    }
#pragma unroll
    for (int si = 0; si < 5; ++si)
        wfT[(si * 256 + ci) * 256 + j] = acc[si] * 0.2f;
}

// ---------------------------------------------------------------------------
// fp32 tiled GEMM (kept for the small P-build path): C[row,col]=sum A[row,k]W[col,k]
template <bool BIAS>
__global__ __launch_bounds__(256) void gemm64(const float* __restrict__ A,
                                              const float* __restrict__ W,
                                              const float* __restrict__ bias,
                                              float* __restrict__ C,
                                              int K, int ldC,
                                              long sliceA, long sliceW, long sliceC) {
    A += (long)blockIdx.z * sliceA;
    W += (long)blockIdx.z * sliceW;
    C += (long)blockIdx.z * sliceC;
    const int row0 = blockIdx.x * 64;
    const int col0 = blockIdx.y * 64;
    __shared__ float As[32][68];
    __shared__ float Ws[32][68];
    const int t = threadIdx.x;
    const int tx = t & 15;
    const int ty = t >> 4;
    float acc[4][4] = {};
    for (int kk = 0; kk < K; kk += 32) {
#pragma unroll
        for (int e = 0; e < 8; ++e) {
            int f = t + 256 * e;
            int r = f >> 5, kc = f & 31;
            As[kc][r] = A[(long)(row0 + r) * K + kk + kc];
            Ws[kc][r] = W[(long)(col0 + r) * K + kk + kc];
        }
        __syncthreads();
#pragma unroll
        for (int kc = 0; kc < 32; ++kc) {
            float4 a4 = *(const float4*)&As[kc][ty * 4];
            float4 w4 = *(const float4*)&Ws[kc][tx * 4];
            float av[4] = {a4.x, a4.y, a4.z, a4.w};
            float wv[4] = {w4.x, w4.y, w4.z, w4.w};
#pragma unroll
            for (int i = 0; i < 4; ++i)
#pragma unroll
                for (int jj = 0; jj < 4; ++jj)
                    acc[i][jj] += av[i] * wv[jj];
        }
        __syncthreads();
    }
#pragma unroll
    for (int r = 0; r < 4; ++r) {
        int row = row0 + ty * 4 + r;
#pragma unroll
        for (int c = 0; c < 4; ++c) {
            int col = col0 + tx * 4 + c;
            float v = acc[r][c];
            if (BIAS) v += bias[col];
            C[(long)row * ldC + col] = v;
        }
    }
}

// ---------------------------------------------------------------------------
// bf16 MFMA GEMM: C[row,col] = sum_k A[row,k]*W[col,k] + bias[col]
// 64x64 tile, BK=32, 4 waves x 4 mfma_16x16x32 per chunk.
template <bool BF16OUT>
__global__ __launch_bounds__(256) void gemm_bf(const short* __restrict__ A,
                                               const short* __restrict__ W,
                                               const float* __restrict__ bias,
                                               void* __restrict__ Cp,
                                               int K, int ldC,
                                               long sliceA, long sliceW, long sliceC) {
    A += (long)blockIdx.z * sliceA;
    W += (long)blockIdx.z * sliceW;
    const int row0 = blockIdx.x * 64, col0 = blockIdx.y * 64;
    __shared__ short As[64 * 40];   // stride 40 bf16 (80B): 16B-aligned rows, 2-way banks
    __shared__ short Ws[64 * 40];
    const int t = threadIdx.x;
    const int wid = t >> 6, lane = t & 63, sub = lane & 15, quad = lane >> 4;
    const int wy = wid >> 1, wx = wid & 1;
    const int srow = t >> 2, sseg = t & 3;
    f32x4 acc00 = {0.f, 0.f, 0.f, 0.f}, acc01 = acc00, acc10 = acc00, acc11 = acc00;
    for (int kk = 0; kk < K; kk += 32) {
        *(short8*)&As[srow * 40 + sseg * 8] = *(const short8*)&A[(long)(row0 + srow) * K + kk + sseg * 8];
        *(short8*)&Ws[srow * 40 + sseg * 8] = *(const short8*)&W[(long)(col0 + srow) * K + kk + sseg * 8];
        __syncthreads();
        short8 a0 = *(const short8*)&As[(wy * 32 + sub) * 40 + quad * 8];
        short8 a1 = *(const short8*)&As[(wy * 32 + 16 + sub) * 40 + quad * 8];
        short8 b0 = *(const short8*)&Ws[(wx * 32 + sub) * 40 + quad * 8];
        short8 b1 = *(const short8*)&Ws[(wx * 32 + 16 + sub) * 40 + quad * 8];
        acc00 = __builtin_amdgcn_mfma_f32_16x16x32_bf16(a0, b0, acc00, 0, 0, 0);
        acc01 = __builtin_amdgcn_mfma_f32_16x16x32_bf16(a0, b1, acc01, 0, 0, 0);
        acc10 = __builtin_amdgcn_mfma_f32_16x16x32_bf16(a1, b0, acc10, 0, 0, 0);
        acc11 = __builtin_amdgcn_mfma_f32_16x16x32_bf16(a1, b1, acc11, 0, 0, 0);
        __syncthreads();
    }
    short* Cs = nullptr; float* Cf = nullptr;
    if (BF16OUT) Cs = (short*)Cp + (long)blockIdx.z * sliceC;
    else Cf = (float*)Cp + (long)blockIdx.z * sliceC;
#pragma unroll
    for (int i = 0; i < 2; ++i)
#pragma unroll
        for (int j = 0; j < 2; ++j) {
            f32x4 a = (i == 0) ? (j == 0 ? acc00 : acc01) : (j == 0 ? acc10 : acc11);
#pragma unroll
            for (int r = 0; r < 4; ++r) {
                int row = row0 + wy * 32 + i * 16 + quad * 4 + r;
                int col = col0 + wx * 32 + j * 16 + sub;
                float v = a[r] + bias[col];
                if (BF16OUT) Cs[(long)row * ldC + col] = f2bf(v);
                else Cf[(long)row * ldC + col] = v;
            }
        }
}

// ---------------------------------------------------------------------------
__global__ void bias_dir_kernel(const float* __restrict__ tp, const float* __restrict__ tpb,
                                const float* __restrict__ dirL, const float* __restrict__ dirR,
                                float* __restrict__ biasL, float* __restrict__ biasR) {
    const float* dir = blockIdx.x ? dirR : dirL;
    float* outp = blockIdx.x ? biasR : biasL;
    __shared__ float sdir[256];
    const int d = threadIdx.x;
    sdir[d] = dir[d];
    __syncthreads();
    float acc = tpb[d];
    for (int j = 0; j < 256; ++j) acc += tp[d * 256 + j] * sdir[j];
    outp[d] = acc;
}

// ---------------------------------------------------------------------------
// Q build: gather 5 rows of P, add dir-bias, LayerNorm -> bf16 Q
__global__ __launch_bounds__(256) void q_build(const int* __restrict__ idsL, const int* __restrict__ idsR,
                                               const float* __restrict__ P_L, const float* __restrict__ P_R,
                                               const float* __restrict__ biasL, const float* __restrict__ biasR,
                                               const float* __restrict__ qg, const float* __restrict__ qb,
                                               short* __restrict__ Qbf) {
    const int bl = blockIdx.x;
    const bool right = blockIdx.y != 0;
    const int* ids = right ? idsR : idsL;
    const float* P = right ? P_R : P_L;
    const float* bias = right ? biasR : biasL;
    const long off = right ? 2097152L : 0L;
    const int d = threadIdx.x;
    __shared__ int toks[5];
    if (d < 5) toks[d] = ids[bl * 5 + d];
    __syncthreads();
    float acc = bias[d];
#pragma unroll
    for (int s = 0; s < 5; ++s)
        acc += P[((s * 512) + toks[s]) * 256 + d];
    __shared__ float red[256];
    red[d] = acc;
    __syncthreads();
    for (int st = 128; st; st >>= 1) { if (d < st) red[d] += red[d + st]; __syncthreads(); }
    float mean = red[0] * (1.0f / 256.0f);
    __syncthreads();
    float dv = acc - mean;
    red[d] = dv * dv;
    __syncthreads();
    for (int st = 128; st; st >>= 1) { if (d < st) red[d] += red[d + st]; __syncthreads(); }
    float var = red[0] * (1.0f / 256.0f);
    Qbf[off + (long)bl * 256 + d] = f2bf(dv * rsqrtf(var + 1e-5f) * qg[d] + qb[d]);
}

// ---------------------------------------------------------------------------
// In-place row LayerNorm on bf16 rows (y=0: K, y=1: V)
__global__ __launch_bounds__(256) void ln_rows_bf(short* __restrict__ Kb, short* __restrict__ Vb,
                                                  const float* __restrict__ gamma, const float* __restrict__ beta) {
    short* ptr = (blockIdx.y ? Vb : Kb) + (long)blockIdx.x * 256;
    const int t = threadIdx.x;
    float x = bf2f(ptr[t]);
    __shared__ float red[256];
    red[t] = x;
    __syncthreads();
    for (int st = 128; st; st >>= 1) { if (t < st) red[t] += red[t + st]; __syncthreads(); }
    float mean = red[0] * (1.0f / 256.0f);
    __syncthreads();
    float dv = x - mean;
    red[t] = dv * dv;
    __syncthreads();
    for (int st = 128; st; st >>= 1) { if (t < st) red[t] += red[t + st]; __syncthreads(); }
    float var = red[0] * (1.0f / 256.0f);
    ptr[t] = f2bf(dv * rsqrtf(var + 1e-5f) * gamma[t] + beta[t]);
}

// ---------------------------------------------------------------------------
// V transpose: Vbf[b*1024+n][256] (head cols h*32..+32) -> Vt[((b*8+h)*32+d)*1024+n]
__global__ __launch_bounds__(256) void v_transpose(const short* __restrict__ Vbf, short* __restrict__ Vt) {
    const int nc = blockIdx.x;  // 0..3 chunks of 256 n
    const int h = blockIdx.y;
    const int b = blockIdx.z;
    __shared__ short s[256 * 40];
    const int t = threadIdx.x;
    {
        const int seg = t & 3;
#pragma unroll
        for (int it = 0; it < 4; ++it) {
            int n = it * 64 + (t >> 2);
            *(short8*)&s[n * 40 + seg * 8] =
                *(const short8*)&Vbf[(long)(b * 1024 + nc * 256 + n) * 256 + h * 32 + seg * 8];
        }
    }
    __syncthreads();
    {
        const int d = t & 31, seg = t >> 5;   // seg 0..7
        short buf[32];
#pragma unroll
        for (int j = 0; j < 32; ++j) buf[j] = s[(seg * 32 + j) * 40 + d];
        short8* dst = (short8*)&Vt[((long)(b * 8 + h) * 32 + d) * 1024 + nc * 256 + seg * 32];
#pragma unroll
        for (int q = 0; q < 4; ++q) {
            short8 v;
#pragma unroll
            for (int j = 0; j < 8; ++j) v[j] = buf[q * 8 + j];
            dst[q] = v;
        }
    }
}

// ---------------------------------------------------------------------------
// MFMA cross-attention. Block = (l-tile 16, head, b*2+side). 256 thr (4 waves).
// Phase 1: scores (Q.K^T) * invscale * mask -> LDS bf16 [16][1032]
// Phase 2: block softmax (unnormalized p stored, 1/sum kept)
// Phase 3: P.V via MFMA (waves split d-tile x k-half), combine, scale, store bf16 F.
__global__ __launch_bounds__(256) void attn_mfma(const short* __restrict__ Qbf,
                                                 const short* __restrict__ Kbf,
                                                 const short* __restrict__ Vt,
                                                 const float* __restrict__ vis_mask,
                                                 const float* __restrict__ tau_p,
                                                 short* __restrict__ Fbf) {
    const int lt = blockIdx.x;            // 0..15
    const int h = blockIdx.y;             // 0..7
    const int b = blockIdx.z >> 1;        // 0..31
    const int side = blockIdx.z & 1;
    const int l0 = lt * 16;
    const int t = threadIdx.x;
    const int wid = t >> 6, lane = t & 63, sub = lane & 15, quad = lane >> 4;
    float tau = fminf(fmaxf(tau_p[0], 0.25f), 4.0f);
    const float invscale = 1.0f / (5.656854249492381f * tau);

    __shared__ short s_pb[16 * 1032];     // stride 1032 bf16: 16B-aligned, 2-way banks
    __shared__ float s_op[2 * 16 * 33];
    __shared__ float s_rsum[16];

    const short* Qside = Qbf + (long)side * 2097152;
    short8 aq = *(const short8*)&Qside[(long)(b * 256 + l0 + sub) * 256 + h * 32 + quad * 8];

    // ---- phase 1: scores for this wave's 256-col slice ----
    const int ncol0 = wid * 256;
#pragma unroll 4
    for (int nt = 0; nt < 16; ++nt) {
        int n0 = ncol0 + nt * 16;
        short8 bk = *(const short8*)&Kbf[(long)(b * 1024 + n0 + sub) * 256 + h * 32 + quad * 8];
        f32x4 c = {0.f, 0.f, 0.f, 0.f};
        c = __builtin_amdgcn_mfma_f32_16x16x32_bf16(aq, bk, c, 0, 0, 0);
#pragma unroll
        for (int r = 0; r < 4; ++r) {
            int lrow = quad * 4 + r;
            float mk = vis_mask[(long)(b * 256 + l0 + lrow) * 1024 + n0 + sub];
            s_pb[lrow * 1032 + n0 + sub] = f2bf(c[r] * invscale * mk);
        }
    }
    __syncthreads();

    // ---- phase 2: softmax (row owned by 16 contiguous lanes) ----
    {
        const int row = t >> 4, seg = t & 15;
        short* rp = &s_pb[row * 1032 + seg * 64];
        float m = -1e30f;
#pragma unroll
        for (int i = 0; i < 8; ++i) {
            short8 v = *(short8*)&rp[i * 8];
#pragma unroll
            for (int j = 0; j < 8; ++j) m = fmaxf(m, bf2f(v[j]));
        }
#pragma unroll
        for (int off = 8; off; off >>= 1) m = fmaxf(m, __shfl_xor(m, off, 16));
        float sum = 0.f;
#pragma unroll
        for (int i = 0; i < 8; ++i) {
            short8 v = *(short8*)&rp[i * 8];
            short8 o;
#pragma unroll
            for (int j = 0; j < 8; ++j) {
                float p = __expf(bf2f(v[j]) - m);
                sum += p;
                o[j] = f2bf(p);
            }
            *(short8*)&rp[i * 8] = o;
        }
#pragma unroll
        for (int off = 8; off; off >>= 1) sum += __shfl_xor(sum, off, 16);
        if (seg == 0) s_rsum[row] = 1.0f / sum;
    }
    __syncthreads();

    // ---- phase 3: O = P.V ----
    {
        const int di = wid & 1, kh = wid >> 1;
        f32x4 acc = {0.f, 0.f, 0.f, 0.f};
        const short* vrow = &Vt[((long)(b * 8 + h) * 32 + di * 16 + sub) * 1024 + kh * 512];
#pragma unroll 4
        for (int ks = 0; ks < 16; ++ks) {
            int kc = kh * 512 + ks * 32 + quad * 8;
            short8 ap = *(const short8*)&s_pb[sub * 1032 + kc];
            short8 bv = *(const short8*)&vrow[ks * 32 + quad * 8];
            acc = __builtin_amdgcn_mfma_f32_16x16x32_bf16(ap, bv, acc, 0, 0, 0);
        }
#pragma unroll
        for (int r = 0; r < 4; ++r)
            s_op[(kh * 16 + quad * 4 + r) * 33 + di * 16 + sub] = acc[r];
    }
    __syncthreads();

    for (int i = t; i < 512; i += 256) {
        int l = i >> 5, d = i & 31;
        float v = (s_op[l * 33 + d] + s_op[(16 + l) * 33 + d]) * s_rsum[l];
        Fbf[(long)side * 2097152 + (long)(b * 256 + l0 + l) * 256 + h * 32 + d] = f2bf(v);
    }
}

// ---------------------------------------------------------------------------
__global__ __launch_bounds__(256) void loss_pair(const float* __restrict__ logits,
                                                 const float* __restrict__ tgt_mask,
                                                 float* __restrict__ accp) {
    const int l = blockIdx.x;   // 0..254
    const int b = blockIdx.y;
    const int t = threadIdx.x;
    const float* ll = logits + (long)(b * 256 + l) * 512;
    const float* lr = logits + 4194304 + (long)(b * 256 + l + 1) * 512;
    float a0 = ll[t] * 0.5f, a1 = ll[t + 256] * 0.5f;
    float c0 = lr[t] * 0.5f, c1 = lr[t + 256] * 0.5f;
    __shared__ float red[256];
    auto bmax = [&](float v) -> float {
        red[t] = v; __syncthreads();
        for (int st = 128; st; st >>= 1) { if (t < st) red[t] = fmaxf(red[t], red[t + st]); __syncthreads(); }
        float r = red[0]; __syncthreads(); return r;
    };
    auto bsum = [&](float v) -> float {
        red[t] = v; __syncthreads();
        for (int st = 128; st; st >>= 1) { if (t < st) red[t] += red[t + st]; __syncthreads(); }
        float r = red[0]; __syncthreads(); return r;
    };
    float ml = bmax(fmaxf(a0, a1));
    float e0 = expf(a0 - ml), e1 = expf(a1 - ml);
    float sl = bsum(e0 + e1);
    float p0 = e0 / sl, p1 = e1 / sl;
    float mr = bmax(fmaxf(c0, c1));
    float f0 = expf(c0 - mr), f1 = expf(c1 - mr);
    float sr = bsum(f0 + f1);
    float q0 = f0 / sr, q1 = f1 / sr;
    float d0 = p0 - q0, d1 = p1 - q1;
    float sq = bsum(d0 * d0 + d1 * d1);
    if (t == 0) atomicAdd(accp, sq * tgt_mask[b * 256 + l]);
}

__global__ __launch_bounds__(256) void loss_final(const float* __restrict__ tgt_mask,
                                                  const float* __restrict__ accp,
                                                  float* __restrict__ outp) {
    const int t = threadIdx.x;
    float s = 0.f;
    for (int i = t; i < 32 * 255; i += 256) {
        int b = i / 255, l = i % 255;
        s += tgt_mask[b * 256 + l];
    }
    __shared__ float red[256];
    red[t] = s;
    __syncthreads();
    for (int st = 128; st; st >>= 1) { if (t < st) red[t] += red[t + st]; __syncthreads(); }
    if (t == 0) outp[0] = 0.1f * accp[0] / fmaxf(red[0], 1.0f);
}

// ---------------------------------------------------------------------------
extern "C" void kernel_launch(void* const* d_in, const int* in_sizes, int n_in,
                              void* d_out, int out_size, void* d_ws, size_t ws_size,
                              hipStream_t stream) {
    const float* vis_tokens = (const float*)d_in[0];
    const int* idsL = (const int*)d_in[1];
    const int* idsR = (const int*)d_in[2];
    const float* tgt_mask = (const float*)d_in[4];
    const float* vis_mask = (const float*)d_in[5];
    const float* emb_w = (const float*)d_in[6];
    const float* dirL = (const float*)d_in[7];
    const float* dirR = (const float*)d_in[8];
    const float* tp_w = (const float*)d_in[9];
    const float* tp_b = (const float*)d_in[10];
    const float* q_g = (const float*)d_in[11];
    const float* q_b = (const float*)d_in[12];
    const float* k_w = (const float*)d_in[13];
    const float* k_b = (const float*)d_in[14];
    const float* v_w = (const float*)d_in[15];
    const float* v_b = (const float*)d_in[16];
    const float* kv_g = (const float*)d_in[17];
    const float* kv_b = (const float*)d_in[18];
    const float* tau = (const float*)d_in[19];
    const float* cls_b = (const float*)d_in[20];
    const float* conv_l = (const float*)d_in[21];
    const float* conv_r = (const float*)d_in[22];
    float* out = (float*)d_out;

    // ---- workspace layout ----
    short* sws = (short*)d_ws;
    short* visbf = sws;                         // 8,388,608
    short* embbf = visbf + 8388608;             // 131,072
    short* kwbf  = embbf + 131072;              // 65,536
    short* vwbf  = kwbf + 65536;                // 65,536
    short* Kbf   = vwbf + 65536;                // 8,388,608
    short* Vbf   = Kbf + 8388608;               // 8,388,608
    short* Vt    = Vbf + 8388608;               // 8,388,608
    short* Qbf   = Vt + 8388608;                // 4,194,304 (L|R)
    short* Fbf   = Qbf + 4194304;               // 4,194,304 (L|R)
    float* wfT   = (float*)(Fbf + 4194304);     // 10 slices x 65536
    float* Ms    = wfT + 655360;                // 10 x 65536
    float* Pp    = Ms + 655360;                 // 10 x 131072
    float* bias_l = Pp + 1310720;
    float* bias_r = bias_l + 256;
    float* accp = bias_r + 256;

    hipMemsetAsync(accp, 0, sizeof(float), stream);

    // ---- fp32 -> bf16 converts ----
    cvt_bf16<<<8192, 256, 0, stream>>>(vis_tokens, visbf, 2097152);
    cvt_bf16<<<128, 256, 0, stream>>>(emb_w, embbf, 32768);
    cvt_bf16<<<64, 256, 0, stream>>>(k_w, kwbf, 16384);
    cvt_bf16<<<64, 256, 0, stream>>>(v_w, vwbf, 16384);

    // ---- ctx path: wfold -> Ms -> P (fp32, small) ----
    build_wfold<<<256, 256, 0, stream>>>(conv_l, wfT);
    build_wfold<<<256, 256, 0, stream>>>(conv_r, wfT + 327680);
    gemm64<false><<<dim3(4, 4, 10), 256, 0, stream>>>(tp_w, wfT, nullptr, Ms, 256, 256, 0, 65536, 65536);
    gemm64<false><<<dim3(8, 4, 10), 256, 0, stream>>>(emb_w, Ms, nullptr, Pp, 256, 256, 0, 65536, 131072);
    bias_dir_kernel<<<2, 256, 0, stream>>>(tp_w, tp_b, dirL, dirR, bias_l, bias_r);
    q_build<<<dim3(8192, 2), 256, 0, stream>>>(idsL, idsR, Pp, Pp + 655360, bias_l, bias_r, q_g, q_b, Qbf);

    // ---- K/V projections (bf16 MFMA) + LN + V transpose ----
    gemm_bf<true><<<dim3(512, 4, 1), 256, 0, stream>>>(visbf, kwbf, k_b, Kbf, 256, 256, 0, 0, 0);
    gemm_bf<true><<<dim3(512, 4, 1), 256, 0, stream>>>(visbf, vwbf, v_b, Vbf, 256, 256, 0, 0, 0);
    ln_rows_bf<<<dim3(32768, 2), 256, 0, stream>>>(Kbf, Vbf, kv_g, kv_b);
    v_transpose<<<dim3(4, 8, 32), 256, 0, stream>>>(Vbf, Vt);

    // ---- fused MFMA cross-attention (both sides) ----
    attn_mfma<<<dim3(16, 8, 64), 256, 0, stream>>>(Qbf, Kbf, Vt, vis_mask, tau, Fbf);

    // ---- tied classifier logits (bf16 MFMA, fp32 out) into d_out+1 ----
    gemm_bf<false><<<dim3(128, 8, 2), 256, 0, stream>>>(Fbf, embbf, cls_b, out + 1, 256, 512,
                                                        2097152, 0, 4194304);

    // ---- SGM agreement loss ----
    loss_pair<<<dim3(255, 32), 256, 0, stream>>>(out + 1, tgt_mask, accp);
    loss_final<<<1, 256, 0, stream>>>(tgt_mask, accp, out);
}

// Round 5
// 544.728 us; speedup vs baseline: 4.7227x; 1.1065x over previous
//
#include <hip/hip_runtime.h>

typedef __attribute__((ext_vector_type(8))) short short8;
typedef __attribute__((ext_vector_type(4))) float f32x4;

__device__ __forceinline__ short f2bf(float x) {
    union { float f; unsigned u; } c; c.f = x;
    unsigned u = c.u;
    u += 0x7fffu + ((u >> 16) & 1u);
    return (short)(u >> 16);
}
__device__ __forceinline__ float bf2f(short x) {
    union { unsigned u; float f; } c; c.u = ((unsigned)(unsigned short)x) << 16;
    return c.f;
}

// ---------------------------------------------------------------------------
// fp32 -> bf16 bulk convert for vis_tokens
__global__ __launch_bounds__(256) void cvt_bf16(const float* __restrict__ s, short* __restrict__ d, int n4) {
    int i = blockIdx.x * 256 + threadIdx.x;
    if (i < n4) {
        float4 v = ((const float4*)s)[i];
        short4 o;
        o.x = f2bf(v.x); o.y = f2bf(v.y); o.z = f2bf(v.z); o.w = f2bf(v.w);
        ((short4*)d)[i] = o;
    }
}

// combined small converts (float4 counts): emb_w 32768, k_w 16384, v_w 16384
__global__ __launch_bounds__(256) void cvt3(const float* __restrict__ emb, const float* __restrict__ kw,
                                            const float* __restrict__ vw,
                                            short* __restrict__ de, short* __restrict__ dk, short* __restrict__ dv) {
    int i = blockIdx.x * 256 + threadIdx.x;   // 0..65535
    const float* s; short* d; int off;
    if (i < 32768) { s = emb; d = de; off = i; }
    else if (i < 49152) { s = kw; d = dk; off = i - 32768; }
    else { s = vw; d = dv; off = i - 49152; }
    float4 v = ((const float4*)s)[off];
    short4 o;
    o.x = f2bf(v.x); o.y = f2bf(v.y); o.z = f2bf(v.z); o.w = f2bf(v.w);
    ((short4*)d)[off] = o;
}

// ---------------------------------------------------------------------------
// Fold conv into W_fold^T; blockIdx.y selects side.
__global__ void build_wfold(const float* __restrict__ cl, const float* __restrict__ cr,
                            float* __restrict__ wfT) {
    const float* conv_w = blockIdx.y ? cr : cl;
    float* o = wfT + (long)blockIdx.y * 327680;
    const int j = blockIdx.x;
    const int ci = threadIdx.x;
    float acc[5] = {0.f, 0.f, 0.f, 0.f, 0.f};
#pragma unroll
    for (int i = 0; i < 5; ++i) {
        int flat = i * 256 + j;
        int c = flat / 5;
        int s = flat % 5;
#pragma unroll
        for (int k = 0; k < 3; ++k) {
            int si = s + k - 1;
            if (si >= 0 && si < 5) acc[si] += conv_w[(c * 256 + ci) * 3 + k];
        }
    }
#pragma unroll
    for (int si = 0; si < 5; ++si)
        o[(si * 256 + ci) * 256 + j] = acc[si] * 0.2f;
}

// ---------------------------------------------------------------------------
// fp32 tiled GEMM (small P-build path): C[row,col]=sum A[row,k]W[col,k]
template <bool BIAS>
__global__ __launch_bounds__(256) void gemm64(const float* __restrict__ A,
                                              const float* __restrict__ W,
                                              const float* __restrict__ bias,
                                              float* __restrict__ C,
                                              int K, int ldC,
                                              long sliceA, long sliceW, long sliceC) {
    A += (long)blockIdx.z * sliceA;
    W += (long)blockIdx.z * sliceW;
    C += (long)blockIdx.z * sliceC;
    const int row0 = blockIdx.x * 64;
    const int col0 = blockIdx.y * 64;
    __shared__ float As[32][68];
    __shared__ float Ws[32][68];
    const int t = threadIdx.x;
    const int tx = t & 15;
    const int ty = t >> 4;
    float acc[4][4] = {};
    for (int kk = 0; kk < K; kk += 32) {
#pragma unroll
        for (int e = 0; e < 8; ++e) {
            int f = t + 256 * e;
            int r = f >> 5, kc = f & 31;
            As[kc][r] = A[(long)(row0 + r) * K + kk + kc];
            Ws[kc][r] = W[(long)(col0 + r) * K + kk + kc];
        }
        __syncthreads();
#pragma unroll
        for (int kc = 0; kc < 32; ++kc) {
            float4 a4 = *(const float4*)&As[kc][ty * 4];
            float4 w4 = *(const float4*)&Ws[kc][tx * 4];
            float av[4] = {a4.x, a4.y, a4.z, a4.w};
            float wv[4] = {w4.x, w4.y, w4.z, w4.w};
#pragma unroll
            for (int i = 0; i < 4; ++i)
#pragma unroll
                for (int jj = 0; jj < 4; ++jj)
                    acc[i][jj] += av[i] * wv[jj];
        }
        __syncthreads();
    }
#pragma unroll
    for (int r = 0; r < 4; ++r) {
        int row = row0 + ty * 4 + r;
#pragma unroll
        for (int c = 0; c < 4; ++c) {
            int col = col0 + tx * 4 + c;
            float v = acc[r][c];
            if (BIAS) v += bias[col];
            C[(long)row * ldC + col] = v;
        }
    }
}

// ---------------------------------------------------------------------------
// bf16 MFMA GEMM (classifier): C = A.W^T + bias, fp32 out
__global__ __launch_bounds__(256) void gemm_bf(const short* __restrict__ A,
                                               const short* __restrict__ W,
                                               const float* __restrict__ bias,
                                               float* __restrict__ Cf,
                                               int K, int ldC,
                                               long sliceA, long sliceC) {
    A += (long)blockIdx.z * sliceA;
    const int row0 = blockIdx.x * 64, col0 = blockIdx.y * 64;
    __shared__ short As[64 * 40];
    __shared__ short Ws[64 * 40];
    const int t = threadIdx.x;
    const int wid = t >> 6, lane = t & 63, sub = lane & 15, quad = lane >> 4;
    const int wy = wid >> 1, wx = wid & 1;
    const int srow = t >> 2, sseg = t & 3;
    f32x4 acc00 = {0.f, 0.f, 0.f, 0.f}, acc01 = acc00, acc10 = acc00, acc11 = acc00;
    for (int kk = 0; kk < K; kk += 32) {
        *(short8*)&As[srow * 40 + sseg * 8] = *(const short8*)&A[(long)(row0 + srow) * K + kk + sseg * 8];
        *(short8*)&Ws[srow * 40 + sseg * 8] = *(const short8*)&W[(long)(col0 + srow) * K + kk + sseg * 8];
        __syncthreads();
        short8 a0 = *(const short8*)&As[(wy * 32 + sub) * 40 + quad * 8];
        short8 a1 = *(const short8*)&As[(wy * 32 + 16 + sub) * 40 + quad * 8];
        short8 b0 = *(const short8*)&Ws[(wx * 32 + sub) * 40 + quad * 8];
        short8 b1 = *(const short8*)&Ws[(wx * 32 + 16 + sub) * 40 + quad * 8];
        acc00 = __builtin_amdgcn_mfma_f32_16x16x32_bf16(a0, b0, acc00, 0, 0, 0);
        acc01 = __builtin_amdgcn_mfma_f32_16x16x32_bf16(a0, b1, acc01, 0, 0, 0);
        acc10 = __builtin_amdgcn_mfma_f32_16x16x32_bf16(a1, b0, acc10, 0, 0, 0);
        acc11 = __builtin_amdgcn_mfma_f32_16x16x32_bf16(a1, b1, acc11, 0, 0, 0);
        __syncthreads();
    }
    Cf += (long)blockIdx.z * sliceC;
#pragma unroll
    for (int i = 0; i < 2; ++i)
#pragma unroll
        for (int j = 0; j < 2; ++j) {
            f32x4 a = (i == 0) ? (j == 0 ? acc00 : acc01) : (j == 0 ? acc10 : acc11);
#pragma unroll
            for (int r = 0; r < 4; ++r) {
                int row = row0 + wy * 32 + i * 16 + quad * 4 + r;
                int col = col0 + wx * 32 + j * 16 + sub;
                Cf[(long)row * ldC + col] = a[r] + bias[col];
            }
        }
}

// ---------------------------------------------------------------------------
// K/V projection + bias + row LayerNorm fused; V written transposed into Vt.
// Block: 64 rows x 256 cols, 4 waves (wave = 64-col slice). blockIdx.y: 0=K,1=V.
__global__ __launch_bounds__(256) void gemm_ln(const short* __restrict__ A,
                                               const short* __restrict__ kwbf, const short* __restrict__ vwbf,
                                               const float* __restrict__ k_b, const float* __restrict__ v_b,
                                               const float* __restrict__ gamma, const float* __restrict__ beta,
                                               short* __restrict__ Kout, short* __restrict__ Vt) {
    const bool isV = blockIdx.y != 0;
    const short* W = isV ? vwbf : kwbf;
    const float* bias = isV ? v_b : k_b;
    const int row0 = blockIdx.x * 64;
    __shared__ short As[64 * 40];
    __shared__ short Ws[256 * 40];
    __shared__ float s_mu[64 * 4];
    __shared__ float s_sq[64 * 4];
    __shared__ float s_mv[64 * 2];
    const int t = threadIdx.x;
    const int wid = t >> 6, lane = t & 63, sub = lane & 15, quad = lane >> 4;
    f32x4 acc[4][4];
#pragma unroll
    for (int mi = 0; mi < 4; ++mi)
#pragma unroll
        for (int ni = 0; ni < 4; ++ni) acc[mi][ni] = (f32x4){0.f, 0.f, 0.f, 0.f};

    const int sr = t >> 2, sseg = t & 3;
    for (int kk = 0; kk < 256; kk += 32) {
        *(short8*)&As[sr * 40 + sseg * 8] = *(const short8*)&A[(long)(row0 + sr) * 256 + kk + sseg * 8];
#pragma unroll
        for (int i = 0; i < 4; ++i) {
            int r = i * 64 + sr;
            *(short8*)&Ws[r * 40 + sseg * 8] = *(const short8*)&W[(long)r * 256 + kk + sseg * 8];
        }
        __syncthreads();
        short8 a[4], b[4];
#pragma unroll
        for (int mi = 0; mi < 4; ++mi) a[mi] = *(const short8*)&As[(mi * 16 + sub) * 40 + quad * 8];
#pragma unroll
        for (int ni = 0; ni < 4; ++ni) b[ni] = *(const short8*)&Ws[(wid * 64 + ni * 16 + sub) * 40 + quad * 8];
#pragma unroll
        for (int mi = 0; mi < 4; ++mi)
#pragma unroll
            for (int ni = 0; ni < 4; ++ni)
                acc[mi][ni] = __builtin_amdgcn_mfma_f32_16x16x32_bf16(a[mi], b[ni], acc[mi][ni], 0, 0, 0);
        __syncthreads();
    }
    // add bias
#pragma unroll
    for (int ni = 0; ni < 4; ++ni) {
        float bv = bias[wid * 64 + ni * 16 + sub];
#pragma unroll
        for (int mi = 0; mi < 4; ++mi)
#pragma unroll
            for (int r = 0; r < 4; ++r) acc[mi][ni][r] += bv;
    }
    // per-row partial sums over this wave's 64 cols
#pragma unroll
    for (int mi = 0; mi < 4; ++mi) {
#pragma unroll
        for (int r = 0; r < 4; ++r) {
            float s = 0.f, q2 = 0.f;
#pragma unroll
            for (int ni = 0; ni < 4; ++ni) {
                float v = acc[mi][ni][r];
                s += v; q2 += v * v;
            }
#pragma unroll
            for (int off = 8; off; off >>= 1) {
                s += __shfl_xor(s, off, 16);
                q2 += __shfl_xor(q2, off, 16);
            }
            if (sub == 0) {
                int row = mi * 16 + quad * 4 + r;
                s_mu[row * 4 + wid] = s;
                s_sq[row * 4 + wid] = q2;
            }
        }
    }
    __syncthreads();
    if (t < 64) {
        float s = s_mu[t * 4] + s_mu[t * 4 + 1] + s_mu[t * 4 + 2] + s_mu[t * 4 + 3];
        float q2 = s_sq[t * 4] + s_sq[t * 4 + 1] + s_sq[t * 4 + 2] + s_sq[t * 4 + 3];
        float mean = s * (1.0f / 256.0f);
        float var = q2 * (1.0f / 256.0f) - mean * mean;
        s_mv[t * 2] = mean;
        s_mv[t * 2 + 1] = rsqrtf(var + 1e-5f);
    }
    __syncthreads();
#pragma unroll
    for (int ni = 0; ni < 4; ++ni) {
        int col = wid * 64 + ni * 16 + sub;
        float g = gamma[col], bb = beta[col];
        if (!isV) {
#pragma unroll
            for (int mi = 0; mi < 4; ++mi)
#pragma unroll
                for (int r = 0; r < 4; ++r) {
                    int row = mi * 16 + quad * 4 + r;
                    float v = (acc[mi][ni][r] - s_mv[row * 2]) * s_mv[row * 2 + 1] * g + bb;
                    Kout[(long)(row0 + row) * 256 + col] = f2bf(v);
                }
        } else {
            int h = col >> 5, dh = col & 31;
#pragma unroll
            for (int mi = 0; mi < 4; ++mi) {
                int rowb = row0 + mi * 16 + quad * 4;
                short4 o;
#pragma unroll
                for (int r = 0; r < 4; ++r) {
                    int row = mi * 16 + quad * 4 + r;
                    float v = (acc[mi][ni][r] - s_mv[row * 2]) * s_mv[row * 2 + 1] * g + bb;
                    ((short*)&o)[r] = f2bf(v);
                }
                int gb = rowb >> 10, n = rowb & 1023;
                *(short4*)&Vt[((long)(gb * 8 + h) * 32 + dh) * 1024 + n] = o;
            }
        }
    }
}

// ---------------------------------------------------------------------------
__global__ void bias_dir_kernel(const float* __restrict__ tp, const float* __restrict__ tpb,
                                const float* __restrict__ dirL, const float* __restrict__ dirR,
                                float* __restrict__ biasL, float* __restrict__ biasR) {
    const float* dir = blockIdx.x ? dirR : dirL;
    float* outp = blockIdx.x ? biasR : biasL;
    __shared__ float sdir[256];
    const int d = threadIdx.x;
    sdir[d] = dir[d];
    __syncthreads();
    float acc = tpb[d];
    for (int j = 0; j < 256; ++j) acc += tp[d * 256 + j] * sdir[j];
    outp[d] = acc;
}

// ---------------------------------------------------------------------------
// Q build, wave-per-row: gather 5 P rows, + dir bias, LN, bf16 out.
__global__ __launch_bounds__(256) void q_build(const int* __restrict__ idsL, const int* __restrict__ idsR,
                                               const float* __restrict__ Pp,
                                               const float* __restrict__ biasL, const float* __restrict__ biasR,
                                               const float* __restrict__ qg, const float* __restrict__ qb,
                                               short* __restrict__ Qbf) {
    const int wid = threadIdx.x >> 6, lane = threadIdx.x & 63;
    const int bl = blockIdx.x * 4 + wid;
    const bool right = blockIdx.y != 0;
    const int* ids = right ? idsR : idsL;
    const float* P = right ? Pp + 655360 : Pp;
    const float* bias = right ? biasR : biasL;
    const int d0 = lane * 4;
    float4 acc = *(const float4*)&bias[d0];
#pragma unroll
    for (int s = 0; s < 5; ++s) {
        int tok = ids[bl * 5 + s];
        float4 p = *(const float4*)&P[(long)(s * 512 + tok) * 256 + d0];
        acc.x += p.x; acc.y += p.y; acc.z += p.z; acc.w += p.w;
    }
    float sum = acc.x + acc.y + acc.z + acc.w;
    float sq = acc.x * acc.x + acc.y * acc.y + acc.z * acc.z + acc.w * acc.w;
#pragma unroll
    for (int off = 32; off; off >>= 1) {
        sum += __shfl_xor(sum, off, 64);
        sq += __shfl_xor(sq, off, 64);
    }
    float mean = sum * (1.0f / 256.0f);
    float var = sq * (1.0f / 256.0f) - mean * mean;
    float rstd = rsqrtf(var + 1e-5f);
    float4 g = *(const float4*)&qg[d0];
    float4 bb = *(const float4*)&qb[d0];
    short4 o;
    o.x = f2bf((acc.x - mean) * rstd * g.x + bb.x);
    o.y = f2bf((acc.y - mean) * rstd * g.y + bb.y);
    o.z = f2bf((acc.z - mean) * rstd * g.z + bb.z);
    o.w = f2bf((acc.w - mean) * rstd * g.w + bb.w);
    *(short4*)&Qbf[(right ? 2097152L : 0L) + (long)bl * 256 + d0] = o;
}

// ---------------------------------------------------------------------------
// MFMA cross-attention, softmax fused into score phase (no max-subtract; scores
// are O(+-6) so exp is fp32-safe; softmax is shift-invariant).
// Score MFMA computes C^T (row=n, col=l): each lane owns ONE l and 4 consecutive n.
__global__ __launch_bounds__(256) void attn_mfma(const short* __restrict__ Qbf,
                                                 const short* __restrict__ Kbf,
                                                 const short* __restrict__ Vt,
                                                 const float* __restrict__ vis_mask,
                                                 const float* __restrict__ tau_p,
                                                 short* __restrict__ Fbf) {
    const int lt = blockIdx.x;            // 0..15
    const int h = blockIdx.y;             // 0..7
    const int b = blockIdx.z >> 1;        // 0..31
    const int side = blockIdx.z & 1;
    const int l0 = lt * 16;
    const int t = threadIdx.x;
    const int wid = t >> 6, lane = t & 63, sub = lane & 15, quad = lane >> 4;
    float tau = fminf(fmaxf(tau_p[0], 0.25f), 4.0f);
    const float invscale = 1.0f / (5.656854249492381f * tau);

    __shared__ short s_pb[16 * 1032];     // p (unnormalized exp), [l][n]
    __shared__ float s_op[2 * 16 * 33];
    __shared__ float s_sum[16 * 4];

    const short* Qside = Qbf + (long)side * 2097152;
    short8 aq = *(const short8*)&Qside[(long)(b * 256 + l0 + sub) * 256 + h * 32 + quad * 8];
    const float* mbase = vis_mask + (long)(b * 256 + l0 + sub) * 1024;

    float psum = 0.f;
    const int nbase = wid * 256;
#pragma unroll 4
    for (int nt = 0; nt < 16; ++nt) {
        int n0 = nbase + nt * 16;
        short8 bk = *(const short8*)&Kbf[(long)(b * 1024 + n0 + sub) * 256 + h * 32 + quad * 8];
        f32x4 c = {0.f, 0.f, 0.f, 0.f};
        c = __builtin_amdgcn_mfma_f32_16x16x32_bf16(bk, aq, c, 0, 0, 0);  // C[n][l]
        float4 mk = *(const float4*)&mbase[n0 + quad * 4];
        short4 o;
        float p0 = __expf(c[0] * invscale * mk.x); psum += p0; o.x = f2bf(p0);
        float p1 = __expf(c[1] * invscale * mk.y); psum += p1; o.y = f2bf(p1);
        float p2 = __expf(c[2] * invscale * mk.z); psum += p2; o.z = f2bf(p2);
        float p3 = __expf(c[3] * invscale * mk.w); psum += p3; o.w = f2bf(p3);
        *(short4*)&s_pb[sub * 1032 + n0 + quad * 4] = o;
    }
    psum += __shfl_xor(psum, 16, 64);
    psum += __shfl_xor(psum, 32, 64);
    if (lane < 16) s_sum[sub * 4 + wid] = psum;
    __syncthreads();

    // ---- O = P.V ----
    const int di = wid & 1, kh = wid >> 1;
    f32x4 acc = {0.f, 0.f, 0.f, 0.f};
    const short* vrow = &Vt[((long)(b * 8 + h) * 32 + di * 16 + sub) * 1024 + kh * 512];
#pragma unroll 4
    for (int ks = 0; ks < 16; ++ks) {
        short8 ap = *(const short8*)&s_pb[sub * 1032 + kh * 512 + ks * 32 + quad * 8];
        short8 bv = *(const short8*)&vrow[ks * 32 + quad * 8];
        acc = __builtin_amdgcn_mfma_f32_16x16x32_bf16(ap, bv, acc, 0, 0, 0);
    }
#pragma unroll
    for (int r = 0; r < 4; ++r)
        s_op[(kh * 16 + quad * 4 + r) * 33 + di * 16 + sub] = acc[r];
    __syncthreads();

    for (int i = t; i < 512; i += 256) {
        int l = i >> 5, d = i & 31;
        float rs = 1.0f / (s_sum[l * 4] + s_sum[l * 4 + 1] + s_sum[l * 4 + 2] + s_sum[l * 4 + 3]);
        float v = (s_op[l * 33 + d] + s_op[(16 + l) * 33 + d]) * rs;
        Fbf[(long)side * 2097152 + (long)(b * 256 + l0 + l) * 256 + h * 32 + d] = f2bf(v);
    }
}

// ---------------------------------------------------------------------------
// Loss: wave per (b,l) pair.
__global__ __launch_bounds__(256) void loss_pair(const float* __restrict__ logits,
                                                 const float* __restrict__ tgt_mask,
                                                 float* __restrict__ accp) {
    const int wid = threadIdx.x >> 6, lane = threadIdx.x & 63;
    const int pid = blockIdx.x * 4 + wid;   // 0..8159
    const int b = pid / 255, l = pid - b * 255;
    const float* ll = logits + (long)(b * 256 + l) * 512;
    const float* lr = logits + 4194304 + (long)(b * 256 + l + 1) * 512;
    float a[8], c[8];
#pragma unroll
    for (int j = 0; j < 8; ++j) {
        a[j] = ll[lane + 64 * j] * 0.5f;
        c[j] = lr[lane + 64 * j] * 0.5f;
    }
    float ml = -1e30f, mr = -1e30f;
#pragma unroll
    for (int j = 0; j < 8; ++j) { ml = fmaxf(ml, a[j]); mr = fmaxf(mr, c[j]); }
#pragma unroll
    for (int off = 32; off; off >>= 1) {
        ml = fmaxf(ml, __shfl_xor(ml, off, 64));
        mr = fmaxf(mr, __shfl_xor(mr, off, 64));
    }
    float sl = 0.f, sr = 0.f;
#pragma unroll
    for (int j = 0; j < 8; ++j) {
        a[j] = __expf(a[j] - ml); sl += a[j];
        c[j] = __expf(c[j] - mr); sr += c[j];
    }
#pragma unroll
    for (int off = 32; off; off >>= 1) {
        sl += __shfl_xor(sl, off, 64);
        sr += __shfl_xor(sr, off, 64);
    }
    float rl = 1.0f / sl, rr = 1.0f / sr;
    float sq = 0.f;
#pragma unroll
    for (int j = 0; j < 8; ++j) {
        float d = a[j] * rl - c[j] * rr;
        sq += d * d;
    }
#pragma unroll
    for (int off = 32; off; off >>= 1) sq += __shfl_xor(sq, off, 64);
    if (lane == 0) atomicAdd(accp, sq * tgt_mask[b * 256 + l]);
}

__global__ __launch_bounds__(256) void loss_final(const float* __restrict__ tgt_mask,
                                                  const float* __restrict__ accp,
                                                  float* __restrict__ outp) {
    const int t = threadIdx.x;
    float s = 0.f;
    for (int i = t; i < 32 * 255; i += 256) {
        int b = i / 255, l = i % 255;
        s += tgt_mask[b * 256 + l];
    }
    __shared__ float red[256];
    red[t] = s;
    __syncthreads();
    for (int st = 128; st; st >>= 1) { if (t < st) red[t] += red[t + st]; __syncthreads(); }
    if (t == 0) outp[0] = 0.1f * accp[0] / fmaxf(red[0], 1.0f);
}

// ---------------------------------------------------------------------------
extern "C" void kernel_launch(void* const* d_in, const int* in_sizes, int n_in,
                              void* d_out, int out_size, void* d_ws, size_t ws_size,
                              hipStream_t stream) {
    const float* vis_tokens = (const float*)d_in[0];
    const int* idsL = (const int*)d_in[1];
    const int* idsR = (const int*)d_in[2];
    const float* tgt_mask = (const float*)d_in[4];
    const float* vis_mask = (const float*)d_in[5];
    const float* emb_w = (const float*)d_in[6];
    const float* dirL = (const float*)d_in[7];
    const float* dirR = (const float*)d_in[8];
    const float* tp_w = (const float*)d_in[9];
    const float* tp_b = (const float*)d_in[10];
    const float* q_g = (const float*)d_in[11];
    const float* q_b = (const float*)d_in[12];
    const float* k_b = (const float*)d_in[14];
    const float* v_b = (const float*)d_in[16];
    const float* kv_g = (const float*)d_in[17];
    const float* kv_b = (const float*)d_in[18];
    const float* tau = (const float*)d_in[19];
    const float* cls_b = (const float*)d_in[20];
    const float* conv_l = (const float*)d_in[21];
    const float* conv_r = (const float*)d_in[22];
    const float* k_w = (const float*)d_in[13];
    const float* v_w = (const float*)d_in[15];
    float* out = (float*)d_out;

    // ---- workspace layout ----
    short* sws = (short*)d_ws;
    short* visbf = sws;                         // 8,388,608
    short* embbf = visbf + 8388608;             // 131,072
    short* kwbf  = embbf + 131072;              // 65,536
    short* vwbf  = kwbf + 65536;                // 65,536
    short* Kbf   = vwbf + 65536;                // 8,388,608
    short* Vt    = Kbf + 8388608;               // 8,388,608
    short* Qbf   = Vt + 8388608;                // 4,194,304 (L|R)
    short* Fbf   = Qbf + 4194304;               // 4,194,304 (L|R)
    float* wfT   = (float*)(Fbf + 4194304);     // 10 slices x 65536
    float* Ms    = wfT + 655360;                // 10 x 65536
    float* Pp    = Ms + 655360;                 // 10 x 131072
    float* bias_l = Pp + 1310720;
    float* bias_r = bias_l + 256;
    float* accp = bias_r + 256;

    (void)hipMemsetAsync(accp, 0, sizeof(float), stream);

    // ---- converts ----
    cvt_bf16<<<8192, 256, 0, stream>>>(vis_tokens, visbf, 2097152);
    cvt3<<<256, 256, 0, stream>>>(emb_w, k_w, v_w, embbf, kwbf, vwbf);

    // ---- ctx path: wfold -> Ms -> P (fp32, small) ----
    build_wfold<<<dim3(256, 2), 256, 0, stream>>>(conv_l, conv_r, wfT);
    gemm64<false><<<dim3(4, 4, 10), 256, 0, stream>>>(tp_w, wfT, nullptr, Ms, 256, 256, 0, 65536, 65536);
    gemm64<false><<<dim3(8, 4, 10), 256, 0, stream>>>(emb_w, Ms, nullptr, Pp, 256, 256, 0, 65536, 131072);
    bias_dir_kernel<<<2, 256, 0, stream>>>(tp_w, tp_b, dirL, dirR, bias_l, bias_r);
    q_build<<<dim3(2048, 2), 256, 0, stream>>>(idsL, idsR, Pp, bias_l, bias_r, q_g, q_b, Qbf);

    // ---- K/V projections + LN fused (V written transposed) ----
    gemm_ln<<<dim3(512, 2), 256, 0, stream>>>(visbf, kwbf, vwbf, k_b, v_b, kv_g, kv_b, Kbf, Vt);

    // ---- fused MFMA cross-attention ----
    attn_mfma<<<dim3(16, 8, 64), 256, 0, stream>>>(Qbf, Kbf, Vt, vis_mask, tau, Fbf);

    // ---- tied classifier logits into d_out+1 ----
    gemm_bf<<<dim3(128, 8, 2), 256, 0, stream>>>(Fbf, embbf, cls_b, out + 1, 256, 512,
                                                 2097152, 4194304);

    // ---- SGM agreement loss ----
    loss_pair<<<2040, 256, 0, stream>>>(out + 1, tgt_mask, accp);
    loss_final<<<1, 256, 0, stream>>>(tgt_mask, accp, out);
}

// Round 7
// 488.462 us; speedup vs baseline: 5.2667x; 1.1152x over previous
//
#include <hip/hip_runtime.h>

typedef __attribute__((ext_vector_type(8))) short short8;
typedef __attribute__((ext_vector_type(4))) short short4v;
typedef __attribute__((ext_vector_type(4))) float f32x4;

__device__ __forceinline__ short f2bf(float x) {
    union { float f; unsigned u; } c; c.f = x;
    unsigned u = c.u;
    u += 0x7fffu + ((u >> 16) & 1u);
    return (short)(u >> 16);
}

// ---------------------------------------------------------------------------
// fp32 -> bf16 bulk convert for vis_tokens
__global__ __launch_bounds__(256) void cvt_bf16(const float* __restrict__ s, short* __restrict__ d, int n4) {
    int i = blockIdx.x * 256 + threadIdx.x;
    if (i < n4) {
        float4 v = ((const float4*)s)[i];
        short4 o;
        o.x = f2bf(v.x); o.y = f2bf(v.y); o.z = f2bf(v.z); o.w = f2bf(v.w);
        ((short4*)d)[i] = o;
    }
}

// combined small converts (float4 counts): emb_w 32768, k_w 16384, v_w 16384
__global__ __launch_bounds__(256) void cvt3(const float* __restrict__ emb, const float* __restrict__ kw,
                                            const float* __restrict__ vw,
                                            short* __restrict__ de, short* __restrict__ dk, short* __restrict__ dv) {
    int i = blockIdx.x * 256 + threadIdx.x;   // 0..65535
    const float* s; short* d; int off;
    if (i < 32768) { s = emb; d = de; off = i; }
    else if (i < 49152) { s = kw; d = dk; off = i - 32768; }
    else { s = vw; d = dv; off = i - 49152; }
    float4 v = ((const float4*)s)[off];
    short4 o;
    o.x = f2bf(v.x); o.y = f2bf(v.y); o.z = f2bf(v.z); o.w = f2bf(v.w);
    ((short4*)d)[off] = o;
}

// ---------------------------------------------------------------------------
// Fold conv into W_fold^T; blockIdx.y selects side.
__global__ void build_wfold(const float* __restrict__ cl, const float* __restrict__ cr,
                            float* __restrict__ wfT) {
    const float* conv_w = blockIdx.y ? cr : cl;
    float* o = wfT + (long)blockIdx.y * 327680;
    const int j = blockIdx.x;
    const int ci = threadIdx.x;
    float acc[5] = {0.f, 0.f, 0.f, 0.f, 0.f};
#pragma unroll
    for (int i = 0; i < 5; ++i) {
        int flat = i * 256 + j;
        int c = flat / 5;
        int s = flat % 5;
#pragma unroll
        for (int k = 0; k < 3; ++k) {
            int si = s + k - 1;
            if (si >= 0 && si < 5) acc[si] += conv_w[(c * 256 + ci) * 3 + k];
        }
    }
#pragma unroll
    for (int si = 0; si < 5; ++si)
        o[(si * 256 + ci) * 256 + j] = acc[si] * 0.2f;
}

// ---------------------------------------------------------------------------
// fp32 tiled GEMM (small P-build path): C[row,col]=sum A[row,k]W[col,k]
template <bool BIAS>
__global__ __launch_bounds__(256) void gemm64(const float* __restrict__ A,
                                              const float* __restrict__ W,
                                              const float* __restrict__ bias,
                                              float* __restrict__ C,
                                              int K, int ldC,
                                              long sliceA, long sliceW, long sliceC) {
    A += (long)blockIdx.z * sliceA;
    W += (long)blockIdx.z * sliceW;
    C += (long)blockIdx.z * sliceC;
    const int row0 = blockIdx.x * 64;
    const int col0 = blockIdx.y * 64;
    __shared__ float As[32][68];
    __shared__ float Ws[32][68];
    const int t = threadIdx.x;
    const int tx = t & 15;
    const int ty = t >> 4;
    float acc[4][4] = {};
    for (int kk = 0; kk < K; kk += 32) {
#pragma unroll
        for (int e = 0; e < 8; ++e) {
            int f = t + 256 * e;
            int r = f >> 5, kc = f & 31;
            As[kc][r] = A[(long)(row0 + r) * K + kk + kc];
            Ws[kc][r] = W[(long)(col0 + r) * K + kk + kc];
        }
        __syncthreads();
#pragma unroll
        for (int kc = 0; kc < 32; ++kc) {
            float4 a4 = *(const float4*)&As[kc][ty * 4];
            float4 w4 = *(const float4*)&Ws[kc][tx * 4];
            float av[4] = {a4.x, a4.y, a4.z, a4.w};
            float wv[4] = {w4.x, w4.y, w4.z, w4.w};
#pragma unroll
            for (int i = 0; i < 4; ++i)
#pragma unroll
                for (int jj = 0; jj < 4; ++jj)
                    acc[i][jj] += av[i] * wv[jj];
        }
        __syncthreads();
    }
#pragma unroll
    for (int r = 0; r < 4; ++r) {
        int row = row0 + ty * 4 + r;
#pragma unroll
        for (int c = 0; c < 4; ++c) {
            int col = col0 + tx * 4 + c;
            float v = acc[r][c];
            if (BIAS) v += bias[col];
            C[(long)row * ldC + col] = v;
        }
    }
}

// ---------------------------------------------------------------------------
// bf16 MFMA GEMM (classifier): C = A.W^T + bias, fp32 out
__global__ __launch_bounds__(256) void gemm_bf(const short* __restrict__ A,
                                               const short* __restrict__ W,
                                               const float* __restrict__ bias,
                                               float* __restrict__ Cf,
                                               int K, int ldC,
                                               long sliceA, long sliceC) {
    A += (long)blockIdx.z * sliceA;
    const int row0 = blockIdx.x * 64, col0 = blockIdx.y * 64;
    __shared__ short As[64 * 40];
    __shared__ short Ws[64 * 40];
    const int t = threadIdx.x;
    const int wid = t >> 6, lane = t & 63, sub = lane & 15, quad = lane >> 4;
    const int wy = wid >> 1, wx = wid & 1;
    const int srow = t >> 2, sseg = t & 3;
    f32x4 acc00 = {0.f, 0.f, 0.f, 0.f}, acc01 = acc00, acc10 = acc00, acc11 = acc00;
    for (int kk = 0; kk < K; kk += 32) {
        *(short8*)&As[srow * 40 + sseg * 8] = *(const short8*)&A[(long)(row0 + srow) * K + kk + sseg * 8];
        *(short8*)&Ws[srow * 40 + sseg * 8] = *(const short8*)&W[(long)(col0 + srow) * K + kk + sseg * 8];
        __syncthreads();
        short8 a0 = *(const short8*)&As[(wy * 32 + sub) * 40 + quad * 8];
        short8 a1 = *(const short8*)&As[(wy * 32 + 16 + sub) * 40 + quad * 8];
        short8 b0 = *(const short8*)&Ws[(wx * 32 + sub) * 40 + quad * 8];
        short8 b1 = *(const short8*)&Ws[(wx * 32 + 16 + sub) * 40 + quad * 8];
        acc00 = __builtin_amdgcn_mfma_f32_16x16x32_bf16(a0, b0, acc00, 0, 0, 0);
        acc01 = __builtin_amdgcn_mfma_f32_16x16x32_bf16(a0, b1, acc01, 0, 0, 0);
        acc10 = __builtin_amdgcn_mfma_f32_16x16x32_bf16(a1, b0, acc10, 0, 0, 0);
        acc11 = __builtin_amdgcn_mfma_f32_16x16x32_bf16(a1, b1, acc11, 0, 0, 0);
        __syncthreads();
    }
    Cf += (long)blockIdx.z * sliceC;
#pragma unroll
    for (int i = 0; i < 2; ++i)
#pragma unroll
        for (int j = 0; j < 2; ++j) {
            f32x4 a = (i == 0) ? (j == 0 ? acc00 : acc01) : (j == 0 ? acc10 : acc11);
#pragma unroll
            for (int r = 0; r < 4; ++r) {
                int row = row0 + wy * 32 + i * 16 + quad * 4 + r;
                int col = col0 + wx * 32 + j * 16 + sub;
                Cf[(long)row * ldC + col] = a[r] + bias[col];
            }
        }
}

// ---------------------------------------------------------------------------
// K/V projection + bias + row LayerNorm fused; V written transposed into Vt.
__global__ __launch_bounds__(256) void gemm_ln(const short* __restrict__ A,
                                               const short* __restrict__ kwbf, const short* __restrict__ vwbf,
                                               const float* __restrict__ k_b, const float* __restrict__ v_b,
                                               const float* __restrict__ gamma, const float* __restrict__ beta,
                                               short* __restrict__ Kout, short* __restrict__ Vt) {
    const bool isV = blockIdx.y != 0;
    const short* W = isV ? vwbf : kwbf;
    const float* bias = isV ? v_b : k_b;
    const int row0 = blockIdx.x * 64;
    __shared__ short As[64 * 40];
    __shared__ short Ws[256 * 40];
    __shared__ float s_mu[64 * 4];
    __shared__ float s_sq[64 * 4];
    __shared__ float s_mv[64 * 2];
    const int t = threadIdx.x;
    const int wid = t >> 6, lane = t & 63, sub = lane & 15, quad = lane >> 4;
    f32x4 acc[4][4];
#pragma unroll
    for (int mi = 0; mi < 4; ++mi)
#pragma unroll
        for (int ni = 0; ni < 4; ++ni) acc[mi][ni] = (f32x4){0.f, 0.f, 0.f, 0.f};

    const int sr = t >> 2, sseg = t & 3;
    for (int kk = 0; kk < 256; kk += 32) {
        *(short8*)&As[sr * 40 + sseg * 8] = *(const short8*)&A[(long)(row0 + sr) * 256 + kk + sseg * 8];
#pragma unroll
        for (int i = 0; i < 4; ++i) {
            int r = i * 64 + sr;
            *(short8*)&Ws[r * 40 + sseg * 8] = *(const short8*)&W[(long)r * 256 + kk + sseg * 8];
        }
        __syncthreads();
        short8 a[4], b[4];
#pragma unroll
        for (int mi = 0; mi < 4; ++mi) a[mi] = *(const short8*)&As[(mi * 16 + sub) * 40 + quad * 8];
#pragma unroll
        for (int ni = 0; ni < 4; ++ni) b[ni] = *(const short8*)&Ws[(wid * 64 + ni * 16 + sub) * 40 + quad * 8];
#pragma unroll
        for (int mi = 0; mi < 4; ++mi)
#pragma unroll
            for (int ni = 0; ni < 4; ++ni)
                acc[mi][ni] = __builtin_amdgcn_mfma_f32_16x16x32_bf16(a[mi], b[ni], acc[mi][ni], 0, 0, 0);
        __syncthreads();
    }
#pragma unroll
    for (int ni = 0; ni < 4; ++ni) {
        float bv = bias[wid * 64 + ni * 16 + sub];
#pragma unroll
        for (int mi = 0; mi < 4; ++mi)
#pragma unroll
            for (int r = 0; r < 4; ++r) acc[mi][ni][r] += bv;
    }
#pragma unroll
    for (int mi = 0; mi < 4; ++mi) {
#pragma unroll
        for (int r = 0; r < 4; ++r) {
            float s = 0.f, q2 = 0.f;
#pragma unroll
            for (int ni = 0; ni < 4; ++ni) {
                float v = acc[mi][ni][r];
                s += v; q2 += v * v;
            }
#pragma unroll
            for (int off = 8; off; off >>= 1) {
                s += __shfl_xor(s, off, 16);
                q2 += __shfl_xor(q2, off, 16);
            }
            if (sub == 0) {
                int row = mi * 16 + quad * 4 + r;
                s_mu[row * 4 + wid] = s;
                s_sq[row * 4 + wid] = q2;
            }
        }
    }
    __syncthreads();
    if (t < 64) {
        float s = s_mu[t * 4] + s_mu[t * 4 + 1] + s_mu[t * 4 + 2] + s_mu[t * 4 + 3];
        float q2 = s_sq[t * 4] + s_sq[t * 4 + 1] + s_sq[t * 4 + 2] + s_sq[t * 4 + 3];
        float mean = s * (1.0f / 256.0f);
        float var = q2 * (1.0f / 256.0f) - mean * mean;
        s_mv[t * 2] = mean;
        s_mv[t * 2 + 1] = rsqrtf(var + 1e-5f);
    }
    __syncthreads();
#pragma unroll
    for (int ni = 0; ni < 4; ++ni) {
        int col = wid * 64 + ni * 16 + sub;
        float g = gamma[col], bb = beta[col];
        if (!isV) {
#pragma unroll
            for (int mi = 0; mi < 4; ++mi)
#pragma unroll
                for (int r = 0; r < 4; ++r) {
                    int row = mi * 16 + quad * 4 + r;
                    float v = (acc[mi][ni][r] - s_mv[row * 2]) * s_mv[row * 2 + 1] * g + bb;
                    Kout[(long)(row0 + row) * 256 + col] = f2bf(v);
                }
        } else {
            int h = col >> 5, dh = col & 31;
#pragma unroll
            for (int mi = 0; mi < 4; ++mi) {
                int rowb = row0 + mi * 16 + quad * 4;
                short4 o;
#pragma unroll
                for (int r = 0; r < 4; ++r) {
                    int row = mi * 16 + quad * 4 + r;
                    float v = (acc[mi][ni][r] - s_mv[row * 2]) * s_mv[row * 2 + 1] * g + bb;
                    ((short*)&o)[r] = f2bf(v);
                }
                int gb = rowb >> 10, n = rowb & 1023;
                *(short4*)&Vt[((long)(gb * 8 + h) * 32 + dh) * 1024 + n] = o;
            }
        }
    }
}

// ---------------------------------------------------------------------------
__global__ void bias_dir_kernel(const float* __restrict__ tp, const float* __restrict__ tpb,
                                const float* __restrict__ dirL, const float* __restrict__ dirR,
                                float* __restrict__ biasL, float* __restrict__ biasR) {
    const float* dir = blockIdx.x ? dirR : dirL;
    float* outp = blockIdx.x ? biasR : biasL;
    __shared__ float sdir[256];
    const int d = threadIdx.x;
    sdir[d] = dir[d];
    __syncthreads();
    float acc = tpb[d];
    for (int j = 0; j < 256; ++j) acc += tp[d * 256 + j] * sdir[j];
    outp[d] = acc;
}

// ---------------------------------------------------------------------------
// Q build, wave-per-row: gather 5 P rows, + dir bias, LN, bf16 out.
__global__ __launch_bounds__(256) void q_build(const int* __restrict__ idsL, const int* __restrict__ idsR,
                                               const float* __restrict__ Pp,
                                               const float* __restrict__ biasL, const float* __restrict__ biasR,
                                               const float* __restrict__ qg, const float* __restrict__ qb,
                                               short* __restrict__ Qbf) {
    const int wid = threadIdx.x >> 6, lane = threadIdx.x & 63;
    const int bl = blockIdx.x * 4 + wid;
    const bool right = blockIdx.y != 0;
    const int* ids = right ? idsR : idsL;
    const float* P = right ? Pp + 655360 : Pp;
    const float* bias = right ? biasR : biasL;
    const int d0 = lane * 4;
    float4 acc = *(const float4*)&bias[d0];
#pragma unroll
    for (int s = 0; s < 5; ++s) {
        int tok = ids[bl * 5 + s];
        float4 p = *(const float4*)&P[(long)(s * 512 + tok) * 256 + d0];
        acc.x += p.x; acc.y += p.y; acc.z += p.z; acc.w += p.w;
    }
    float sum = acc.x + acc.y + acc.z + acc.w;
    float sq = acc.x * acc.x + acc.y * acc.y + acc.z * acc.z + acc.w * acc.w;
#pragma unroll
    for (int off = 32; off; off >>= 1) {
        sum += __shfl_xor(sum, off, 64);
        sq += __shfl_xor(sq, off, 64);
    }
    float mean = sum * (1.0f / 256.0f);
    float var = sq * (1.0f / 256.0f) - mean * mean;
    float rstd = rsqrtf(var + 1e-5f);
    float4 g = *(const float4*)&qg[d0];
    float4 bb = *(const float4*)&qb[d0];
    short4 o;
    o.x = f2bf((acc.x - mean) * rstd * g.x + bb.x);
    o.y = f2bf((acc.y - mean) * rstd * g.y + bb.y);
    o.z = f2bf((acc.z - mean) * rstd * g.z + bb.z);
    o.w = f2bf((acc.w - mean) * rstd * g.w + bb.w);
    *(short4*)&Qbf[(right ? 2097152L : 0L) + (long)bl * 256 + d0] = o;
}

// ---------------------------------------------------------------------------
// Barrier-free, LDS-free MFMA cross-attention. One WAVE per (b, h, 16-l tile),
// both sides in the same wave (K/Vt/mask shared). Per 32-n chunk:
//   scores: two mfma_16x16x32(K-frag, Q-frag) -> S^T tiles (lane: 4 consec n, one l)
//   p = exp(S*inv*mask); the two exp'd C-frags concatenated ARE the B-frag of a
//   K=32 PV MFMA under the k-slot->n bijection  8q+j -> (j<4 ? 4q+j : 16+4q+j-4),
//   and the matching A-frag is two contiguous short4 loads of Vt concatenated.
//   PV: O^T[dh][l] += mfma_16x16x32(Vt-frag, p8)  -- zero cross-lane movement.
// Row-sums per-lane (l = sub); normalize at end; no __syncthreads anywhere.
__global__ __launch_bounds__(256, 4) void attn_wave(const short* __restrict__ Qbf,
                                                    const short* __restrict__ Kbf,
                                                    const short* __restrict__ Vt,
                                                    const float* __restrict__ vis_mask,
                                                    const float* __restrict__ tau_p,
                                                    short* __restrict__ Fbf) {
    const int t = threadIdx.x;
    const int wid = t >> 6, lane = t & 63, sub = lane & 15, quad = lane >> 4;
    const int w = blockIdx.x * 4 + wid;   // 0..4095
    const int lt = w & 15;
    const int h = (w >> 4) & 7;
    const int b = w >> 7;
    const int l0 = lt * 16;
    float tau = fminf(fmaxf(tau_p[0], 0.25f), 4.0f);
    const float invscale = 1.0f / (5.656854249492381f * tau);

    // Q B-frags (score): Q[l0+sub][h*32 + 8*quad + j]
    const long qoff = (long)(b * 256 + l0 + sub) * 256 + h * 32 + quad * 8;
    const short8 bqL = *(const short8*)&Qbf[qoff];
    const short8 bqR = *(const short8*)&Qbf[2097152 + qoff];

    const short* Kb = Kbf + (long)b * 262144 + h * 32;            // + n*256 + quad*8
    const short* Vb = Vt + (long)(b * 8 + h) * 32768;             // Vt[dh][n]
    const float* mb = vis_mask + (long)(b * 256 + l0 + sub) * 1024 + quad * 4;

    f32x4 oL0 = {0.f, 0.f, 0.f, 0.f}, oL1 = oL0, oR0 = oL0, oR1 = oL0;
    float psL = 0.f, psR = 0.f;

    for (int n0 = 0; n0 < 1024; n0 += 32) {
        short8 ak0 = *(const short8*)&Kb[(long)(n0 + sub) * 256 + quad * 8];
        short8 ak1 = *(const short8*)&Kb[(long)(n0 + 16 + sub) * 256 + quad * 8];
        float4 mk0 = *(const float4*)&mb[n0];
        float4 mk1 = *(const float4*)&mb[n0 + 16];
        // A-frags for PV (k-slot->n bijection): low 4 = tile0 cols, high 4 = tile1 cols
        short4v v00 = *(const short4v*)&Vb[(long)sub * 1024 + n0 + quad * 4];
        short4v v01 = *(const short4v*)&Vb[(long)sub * 1024 + n0 + 16 + quad * 4];
        short4v v10 = *(const short4v*)&Vb[(long)(16 + sub) * 1024 + n0 + quad * 4];
        short4v v11 = *(const short4v*)&Vb[(long)(16 + sub) * 1024 + n0 + 16 + quad * 4];
        short8 av0, av1;
#pragma unroll
        for (int j = 0; j < 4; ++j) {
            av0[j] = v00[j]; av0[4 + j] = v01[j];
            av1[j] = v10[j]; av1[4 + j] = v11[j];
        }

        // ---- side L ----
        {
            f32x4 c0 = {0.f, 0.f, 0.f, 0.f}, c1 = c0;
            c0 = __builtin_amdgcn_mfma_f32_16x16x32_bf16(ak0, bqL, c0, 0, 0, 0);
            c1 = __builtin_amdgcn_mfma_f32_16x16x32_bf16(ak1, bqL, c1, 0, 0, 0);
            short8 p8;
            float p0 = __expf(c0[0] * invscale * mk0.x);
            float p1 = __expf(c0[1] * invscale * mk0.y);
            float p2 = __expf(c0[2] * invscale * mk0.z);
            float p3 = __expf(c0[3] * invscale * mk0.w);
            float p4 = __expf(c1[0] * invscale * mk1.x);
            float p5 = __expf(c1[1] * invscale * mk1.y);
            float p6 = __expf(c1[2] * invscale * mk1.z);
            float p7 = __expf(c1[3] * invscale * mk1.w);
            psL += ((p0 + p1) + (p2 + p3)) + ((p4 + p5) + (p6 + p7));
            p8[0] = f2bf(p0); p8[1] = f2bf(p1); p8[2] = f2bf(p2); p8[3] = f2bf(p3);
            p8[4] = f2bf(p4); p8[5] = f2bf(p5); p8[6] = f2bf(p6); p8[7] = f2bf(p7);
            oL0 = __builtin_amdgcn_mfma_f32_16x16x32_bf16(av0, p8, oL0, 0, 0, 0);
            oL1 = __builtin_amdgcn_mfma_f32_16x16x32_bf16(av1, p8, oL1, 0, 0, 0);
        }
        // ---- side R ----
        {
            f32x4 c0 = {0.f, 0.f, 0.f, 0.f}, c1 = c0;
            c0 = __builtin_amdgcn_mfma_f32_16x16x32_bf16(ak0, bqR, c0, 0, 0, 0);
            c1 = __builtin_amdgcn_mfma_f32_16x16x32_bf16(ak1, bqR, c1, 0, 0, 0);
            short8 p8;
            float p0 = __expf(c0[0] * invscale * mk0.x);
            float p1 = __expf(c0[1] * invscale * mk0.y);
            float p2 = __expf(c0[2] * invscale * mk0.z);
            float p3 = __expf(c0[3] * invscale * mk0.w);
            float p4 = __expf(c1[0] * invscale * mk1.x);
            float p5 = __expf(c1[1] * invscale * mk1.y);
            float p6 = __expf(c1[2] * invscale * mk1.z);
            float p7 = __expf(c1[3] * invscale * mk1.w);
            psR += ((p0 + p1) + (p2 + p3)) + ((p4 + p5) + (p6 + p7));
            p8[0] = f2bf(p0); p8[1] = f2bf(p1); p8[2] = f2bf(p2); p8[3] = f2bf(p3);
            p8[4] = f2bf(p4); p8[5] = f2bf(p5); p8[6] = f2bf(p6); p8[7] = f2bf(p7);
            oR0 = __builtin_amdgcn_mfma_f32_16x16x32_bf16(av0, p8, oR0, 0, 0, 0);
            oR1 = __builtin_amdgcn_mfma_f32_16x16x32_bf16(av1, p8, oR1, 0, 0, 0);
        }
    }

    // full row-sums for l = sub (combine the 4 quads)
    psL += __shfl_xor(psL, 16, 64); psL += __shfl_xor(psL, 32, 64);
    psR += __shfl_xor(psR, 16, 64); psR += __shfl_xor(psR, 32, 64);
    const float rL = 1.0f / psL, rR = 1.0f / psR;

    // O^T[4*quad+r (+16)][l0+sub] -> F[b,l0+sub][h*32 + 4*quad + r (+16)]
    const long fo = (long)(b * 256 + l0 + sub) * 256 + h * 32 + quad * 4;
    short4v s0, s1;
#pragma unroll
    for (int r = 0; r < 4; ++r) { s0[r] = f2bf(oL0[r] * rL); s1[r] = f2bf(oL1[r] * rL); }
    *(short4v*)&Fbf[fo] = s0;
    *(short4v*)&Fbf[fo + 16] = s1;
#pragma unroll
    for (int r = 0; r < 4; ++r) { s0[r] = f2bf(oR0[r] * rR); s1[r] = f2bf(oR1[r] * rR); }
    *(short4v*)&Fbf[2097152 + fo] = s0;
    *(short4v*)&Fbf[2097152 + fo + 16] = s1;
}

// ---------------------------------------------------------------------------
// Loss: wave per (b,l) pair.
__global__ __launch_bounds__(256) void loss_pair(const float* __restrict__ logits,
                                                 const float* __restrict__ tgt_mask,
                                                 float* __restrict__ accp) {
    const int wid = threadIdx.x >> 6, lane = threadIdx.x & 63;
    const int pid = blockIdx.x * 4 + wid;   // 0..8159
    const int b = pid / 255, l = pid - b * 255;
    const float* ll = logits + (long)(b * 256 + l) * 512;
    const float* lr = logits + 4194304 + (long)(b * 256 + l + 1) * 512;
    float a[8], c[8];
#pragma unroll
    for (int j = 0; j < 8; ++j) {
        a[j] = ll[lane + 64 * j] * 0.5f;
        c[j] = lr[lane + 64 * j] * 0.5f;
    }
    float ml = -1e30f, mr = -1e30f;
#pragma unroll
    for (int j = 0; j < 8; ++j) { ml = fmaxf(ml, a[j]); mr = fmaxf(mr, c[j]); }
#pragma unroll
    for (int off = 32; off; off >>= 1) {
        ml = fmaxf(ml, __shfl_xor(ml, off, 64));
        mr = fmaxf(mr, __shfl_xor(mr, off, 64));
    }
    float sl = 0.f, sr = 0.f;
#pragma unroll
    for (int j = 0; j < 8; ++j) {
        a[j] = __expf(a[j] - ml); sl += a[j];
        c[j] = __expf(c[j] - mr); sr += c[j];
    }
#pragma unroll
    for (int off = 32; off; off >>= 1) {
        sl += __shfl_xor(sl, off, 64);
        sr += __shfl_xor(sr, off, 64);
    }
    float rl = 1.0f / sl, rr = 1.0f / sr;
    float sq = 0.f;
#pragma unroll
    for (int j = 0; j < 8; ++j) {
        float d = a[j] * rl - c[j] * rr;
        sq += d * d;
    }
#pragma unroll
    for (int off = 32; off; off >>= 1) sq += __shfl_xor(sq, off, 64);
    if (lane == 0) atomicAdd(accp, sq * tgt_mask[b * 256 + l]);
}

__global__ __launch_bounds__(256) void loss_final(const float* __restrict__ tgt_mask,
                                                  const float* __restrict__ accp,
                                                  float* __restrict__ outp) {
    const int t = threadIdx.x;
    float s = 0.f;
    for (int i = t; i < 32 * 255; i += 256) {
        int b = i / 255, l = i % 255;
        s += tgt_mask[b * 256 + l];
    }
    __shared__ float red[256];
    red[t] = s;
    __syncthreads();
    for (int st = 128; st; st >>= 1) { if (t < st) red[t] += red[t + st]; __syncthreads(); }
    if (t == 0) outp[0] = 0.1f * accp[0] / fmaxf(red[0], 1.0f);
}

// ---------------------------------------------------------------------------
extern "C" void kernel_launch(void* const* d_in, const int* in_sizes, int n_in,
                              void* d_out, int out_size, void* d_ws, size_t ws_size,
                              hipStream_t stream) {
    const float* vis_tokens = (const float*)d_in[0];
    const int* idsL = (const int*)d_in[1];
    const int* idsR = (const int*)d_in[2];
    const float* tgt_mask = (const float*)d_in[4];
    const float* vis_mask = (const float*)d_in[5];
    const float* emb_w = (const float*)d_in[6];
    const float* dirL = (const float*)d_in[7];
    const float* dirR = (const float*)d_in[8];
    const float* tp_w = (const float*)d_in[9];
    const float* tp_b = (const float*)d_in[10];
    const float* q_g = (const float*)d_in[11];
    const float* q_b = (const float*)d_in[12];
    const float* k_w = (const float*)d_in[13];
    const float* k_b = (const float*)d_in[14];
    const float* v_w = (const float*)d_in[15];
    const float* v_b = (const float*)d_in[16];
    const float* kv_g = (const float*)d_in[17];
    const float* kv_b = (const float*)d_in[18];
    const float* tau = (const float*)d_in[19];
    const float* cls_b = (const float*)d_in[20];
    const float* conv_l = (const float*)d_in[21];
    const float* conv_r = (const float*)d_in[22];
    float* out = (float*)d_out;

    // ---- workspace layout ----
    short* sws = (short*)d_ws;
    short* visbf = sws;                         // 8,388,608
    short* embbf = visbf + 8388608;             // 131,072
    short* kwbf  = embbf + 131072;              // 65,536
    short* vwbf  = kwbf + 65536;                // 65,536
    short* Kbf   = vwbf + 65536;                // 8,388,608
    short* Vt    = Kbf + 8388608;               // 8,388,608
    short* Qbf   = Vt + 8388608;                // 4,194,304 (L|R)
    short* Fbf   = Qbf + 4194304;               // 4,194,304 (L|R)
    float* wfT   = (float*)(Fbf + 4194304);     // 10 slices x 65536
    float* Ms    = wfT + 655360;                // 10 x 65536
    float* Pp    = Ms + 655360;                 // 10 x 131072
    float* bias_l = Pp + 1310720;
    float* bias_r = bias_l + 256;
    float* accp = bias_r + 256;

    (void)hipMemsetAsync(accp, 0, sizeof(float), stream);

    // ---- converts ----
    cvt_bf16<<<8192, 256, 0, stream>>>(vis_tokens, visbf, 2097152);
    cvt3<<<256, 256, 0, stream>>>(emb_w, k_w, v_w, embbf, kwbf, vwbf);

    // ---- ctx path: wfold -> Ms -> P (fp32, small) ----
    build_wfold<<<dim3(256, 2), 256, 0, stream>>>(conv_l, conv_r, wfT);
    gemm64<false><<<dim3(4, 4, 10), 256, 0, stream>>>(tp_w, wfT, nullptr, Ms, 256, 256, 0, 65536, 65536);
    gemm64<false><<<dim3(8, 4, 10), 256, 0, stream>>>(emb_w, Ms, nullptr, Pp, 256, 256, 0, 65536, 131072);
    bias_dir_kernel<<<2, 256, 0, stream>>>(tp_w, tp_b, dirL, dirR, bias_l, bias_r);
    q_build<<<dim3(2048, 2), 256, 0, stream>>>(idsL, idsR, Pp, bias_l, bias_r, q_g, q_b, Qbf);

    // ---- K/V projections + LN fused (V written transposed) ----
    gemm_ln<<<dim3(512, 2), 256, 0, stream>>>(visbf, kwbf, vwbf, k_b, v_b, kv_g, kv_b, Kbf, Vt);

    // ---- barrier-free per-wave MFMA cross-attention (both sides) ----
    attn_wave<<<1024, 256, 0, stream>>>(Qbf, Kbf, Vt, vis_mask, tau, Fbf);

    // ---- tied classifier logits into d_out+1 ----
    gemm_bf<<<dim3(128, 8, 2), 256, 0, stream>>>(Fbf, embbf, cls_b, out + 1, 256, 512,
                                                 2097152, 4194304);

    // ---- SGM agreement loss ----
    loss_pair<<<2040, 256, 0, stream>>>(out + 1, tgt_mask, accp);
    loss_final<<<1, 256, 0, stream>>>(tgt_mask, accp, out);
}